// Round 2
// baseline (6239.764 us; speedup 1.0000x reference)
//
#include <hip/hip_runtime.h>
#include <math.h>

#define BSZ  64
#define NSEQ 512
#define FEAT 64
#define HID  128
#define NITER 3
#define RTOT (BSZ*NSEQ)   // 32768 rows

// ---------------- helpers ----------------

__device__ __forceinline__ float sigm(float v) {
  v = fminf(fmaxf(v, -30.f), 30.f);
  return 1.0f / (1.0f + __expf(-v));
}
__device__ __forceinline__ float tanh_fast(float v) {
  v = fminf(fmaxf(v, -15.f), 15.f);
  float e = __expf(2.0f * v);
  return (e - 1.0f) / (e + 1.0f);
}

__device__ __forceinline__ void micro4(const float4 a, const float4 b0, const float4 b1,
                                       const float4 b2, const float4 b3, float acc[4]) {
  acc[0] = fmaf(a.x, b0.x, acc[0]); acc[0] = fmaf(a.y, b1.x, acc[0]);
  acc[0] = fmaf(a.z, b2.x, acc[0]); acc[0] = fmaf(a.w, b3.x, acc[0]);
  acc[1] = fmaf(a.x, b0.y, acc[1]); acc[1] = fmaf(a.y, b1.y, acc[1]);
  acc[1] = fmaf(a.z, b2.y, acc[1]); acc[1] = fmaf(a.w, b3.y, acc[1]);
  acc[2] = fmaf(a.x, b0.z, acc[2]); acc[2] = fmaf(a.y, b1.z, acc[2]);
  acc[2] = fmaf(a.z, b2.z, acc[2]); acc[2] = fmaf(a.w, b3.z, acc[2]);
  acc[3] = fmaf(a.x, b0.w, acc[3]); acc[3] = fmaf(a.y, b1.w, acc[3]);
  acc[3] = fmaf(a.z, b2.w, acc[3]); acc[3] = fmaf(a.w, b3.w, acc[3]);
}

// A-tile [*][LDA] (rows broadcast within half-wave), B-tile [*][HID] (float4 over cols)
template<int LDA>
__device__ __forceinline__ void gemm_tile(const float (*At)[LDA], const float (*Bt)[HID],
                                          int r0, int c0, int koff, float acc[4][4]) {
  #pragma unroll
  for (int k = 0; k < 64; k += 4) {
    float4 b0 = *(const float4*)&Bt[k+0][c0];
    float4 b1 = *(const float4*)&Bt[k+1][c0];
    float4 b2 = *(const float4*)&Bt[k+2][c0];
    float4 b3 = *(const float4*)&Bt[k+3][c0];
    float4 a0 = *(const float4*)&At[r0+0][k+koff];
    float4 a1 = *(const float4*)&At[r0+1][k+koff];
    float4 a2 = *(const float4*)&At[r0+2][k+koff];
    float4 a3 = *(const float4*)&At[r0+3][k+koff];
    micro4(a0, b0,b1,b2,b3, acc[0]);
    micro4(a1, b0,b1,b2,b3, acc[1]);
    micro4(a2, b0,b1,b2,b3, acc[2]);
    micro4(a3, b0,b1,b2,b3, acc[3]);
  }
}

// ---------------- kernels ----------------

// h = relu(x @ W_emb + b_emb) + pos_table[:N]   (32 rows/block)
__global__ __launch_bounds__(256) void k_embed(const float* __restrict__ x, const float* __restrict__ W,
                                               const float* __restrict__ bias, const float* __restrict__ pos,
                                               float* __restrict__ h) {
  __shared__ float xs[32][FEAT];    // 8KB
  __shared__ float Ws[FEAT][HID];   // 32KB
  const int t = threadIdx.x;
  const int row0 = blockIdx.x * 32;
  {
    const float4* wv = (const float4*)W;
    float4* wd = (float4*)&Ws[0][0];
    for (int i = t; i < FEAT*HID/4; i += 256) wd[i] = wv[i];
    const float4* xv = (const float4*)(x + (size_t)row0 * FEAT);
    float4* xd = (float4*)&xs[0][0];
    for (int i = t; i < 32*FEAT/4; i += 256) xd[i] = xv[i];
  }
  __syncthreads();
  const int c0 = (t & 31) * 4;
  const int r0 = (t >> 5) * 4;
  float acc[4][4] = {};
  gemm_tile<FEAT>(xs, Ws, r0, c0, 0, acc);
  const float4 bv = *(const float4*)&bias[c0];
  #pragma unroll
  for (int r = 0; r < 4; ++r) {
    const int row = row0 + r0 + r;
    const int n = row & (NSEQ - 1);
    const float4 pv = *(const float4*)&pos[(size_t)n*HID + c0];
    float4 o;
    o.x = fmaxf(acc[r][0] + bv.x, 0.f) + pv.x;
    o.y = fmaxf(acc[r][1] + bv.y, 0.f) + pv.y;
    o.z = fmaxf(acc[r][2] + bv.z, 0.f) + pv.z;
    o.w = fmaxf(acc[r][3] + bv.w, 0.f) + pv.w;
    *(float4*)&h[(size_t)row*HID + c0] = o;
  }
}

// s[b,n] = ((n - (N-1)/2)/N, 0, 0)
__global__ __launch_bounds__(256) void k_sinit(float* __restrict__ s) {
  const int i = blockIdx.x * 256 + threadIdx.x;
  if (i < RTOT) {
    const int n = i & (NSEQ - 1);
    s[(size_t)i*3 + 0] = ((float)n - (NSEQ - 1) * 0.5f) / (float)NSEQ;
    s[(size_t)i*3 + 1] = 0.f;
    s[(size_t)i*3 + 2] = 0.f;
  }
}

// out = relu(in @ W + b)  (32 rows/block, W staged in two 64-row halves)
__global__ __launch_bounds__(256) void k_msg(const float* __restrict__ in, const float* __restrict__ W,
                                             const float* __restrict__ bias, float* __restrict__ out) {
  __shared__ float as[32][HID];   // 16KB
  __shared__ float Wb[64][HID];   // 32KB
  const int t = threadIdx.x;
  const int row0 = blockIdx.x * 32;
  {
    const float4* av = (const float4*)(in + (size_t)row0 * HID);
    float4* ad = (float4*)&as[0][0];
    for (int i = t; i < 32*HID/4; i += 256) ad[i] = av[i];
  }
  const int c0 = (t & 31) * 4;
  const int r0 = (t >> 5) * 4;
  float acc[4][4] = {};
  #pragma unroll
  for (int half = 0; half < 2; ++half) {
    __syncthreads();
    const float4* wv = (const float4*)(W + (size_t)half*64*HID);
    float4* wd = (float4*)&Wb[0][0];
    for (int i = t; i < 64*HID/4; i += 256) wd[i] = wv[i];
    __syncthreads();
    gemm_tile<HID>(as, Wb, r0, c0, half*64, acc);
  }
  const float4 bv = *(const float4*)&bias[c0];
  #pragma unroll
  for (int r = 0; r < 4; ++r) {
    float4 o;
    o.x = fmaxf(acc[r][0] + bv.x, 0.f);
    o.y = fmaxf(acc[r][1] + bv.y, 0.f);
    o.z = fmaxf(acc[r][2] + bv.z, 0.f);
    o.w = fmaxf(acc[r][3] + bv.w, 0.f);
    *(float4*)&out[(size_t)(row0 + r0 + r)*HID + c0] = o;
  }
}

// agg[b,i,:] = sum_j exp(-100*||s_i-s_j||^2)*mask[b,i,j]*m[b,j,:]  -- A never materialized
__global__ __launch_bounds__(256) void k_agg(const float* __restrict__ s, const float* __restrict__ mask,
                                             const float* __restrict__ m, float* __restrict__ agg) {
  __shared__ float sj[NSEQ][3];   // 6KB
  __shared__ float ws[32][64];    // 8KB
  __shared__ float ms[64][HID];   // 32KB
  const int t = threadIdx.x;
  const int b = blockIdx.x;
  const int i0 = blockIdx.y * 32;
  {
    const float* sp = s + (size_t)b * NSEQ * 3;
    for (int i = t; i < NSEQ*3; i += 256) (&sj[0][0])[i] = sp[i];
  }
  const int c0 = (t & 31) * 4;
  const int r0 = (t >> 5) * 4;
  float acc[4][4] = {};
  for (int j0 = 0; j0 < NSEQ; j0 += 64) {
    __syncthreads();   // covers sj load (first iter) + ws/ms reuse (later iters)
    {
      const float4* mv = (const float4*)(m + ((size_t)b*NSEQ + j0)*HID);
      float4* md = (float4*)&ms[0][0];
      for (int i = t; i < 64*HID/4; i += 256) md[i] = mv[i];
    }
    for (int e = t; e < 32*64; e += 256) {
      const int ii = e >> 6, jj = e & 63;
      const float dx = sj[i0+ii][0] - sj[j0+jj][0];
      const float dy = sj[i0+ii][1] - sj[j0+jj][1];
      const float dz = sj[i0+ii][2] - sj[j0+jj][2];
      const float d2 = dx*dx + dy*dy + dz*dz;
      const float mk = mask[((size_t)b*NSEQ + i0 + ii)*NSEQ + j0 + jj];
      ws[ii][jj] = __expf(-100.0f * d2) * mk;
    }
    __syncthreads();
    gemm_tile<64>(ws, ms, r0, c0, 0, acc);
  }
  #pragma unroll
  for (int r = 0; r < 4; ++r) {
    float4 o = make_float4(acc[r][0], acc[r][1], acc[r][2], acc[r][3]);
    *(float4*)&agg[((size_t)b*NSEQ + i0 + r0 + r)*HID + c0] = o;
  }
}

// fused GRU vertex update: h <- (1-z)h + z*tanh(agg@Wh + (r*h)@Uh + bh)
#define LOADW(SRC, KOFF) do { \
  __syncthreads(); \
  const float4* wv_ = (const float4*)((SRC) + (size_t)(KOFF)*HID); \
  float4* wd_ = (float4*)&Wb[0][0]; \
  for (int i_ = t; i_ < 64*HID/4; i_ += 256) wd_[i_] = wv_[i_]; \
  __syncthreads(); \
} while (0)

__global__ __launch_bounds__(256) void k_gru(float* __restrict__ h, const float* __restrict__ agg,
    const float* __restrict__ Wz, const float* __restrict__ Uz, const float* __restrict__ bz,
    const float* __restrict__ Wr, const float* __restrict__ Ur, const float* __restrict__ br,
    const float* __restrict__ Wh, const float* __restrict__ Uh, const float* __restrict__ bh) {
  __shared__ float as[32][HID];   // agg tile, 16KB
  __shared__ float hs[32][HID];   // h tile (later reused for r*h), 16KB
  __shared__ float Wb[64][HID];   // weight k-half, 32KB  -> 64KB total, 2 blocks/CU
  const int t = threadIdx.x;
  const int row0 = blockIdx.x * 32;
  const int c0 = (t & 31) * 4;
  const int r0 = (t >> 5) * 4;
  {
    const float4* av = (const float4*)(agg + (size_t)row0 * HID);
    float4* ad = (float4*)&as[0][0];
    for (int i = t; i < 32*HID/4; i += 256) ad[i] = av[i];
    const float4* hv = (const float4*)(h + (size_t)row0 * HID);
    float4* hd = (float4*)&hs[0][0];
    for (int i = t; i < 32*HID/4; i += 256) hd[i] = hv[i];
  }
  float acc1[4][4] = {};   // az + hz
  float acc2[4][4] = {};   // ar + hr, later ah + rh@Uh

  LOADW(Wz, 0);  gemm_tile<HID>(as, Wb, r0, c0, 0,  acc1);
  LOADW(Wz, 64); gemm_tile<HID>(as, Wb, r0, c0, 64, acc1);
  LOADW(Uz, 0);  gemm_tile<HID>(hs, Wb, r0, c0, 0,  acc1);
  LOADW(Uz, 64); gemm_tile<HID>(hs, Wb, r0, c0, 64, acc1);
  LOADW(Wr, 0);  gemm_tile<HID>(as, Wb, r0, c0, 0,  acc2);
  LOADW(Wr, 64); gemm_tile<HID>(as, Wb, r0, c0, 64, acc2);
  LOADW(Ur, 0);  gemm_tile<HID>(hs, Wb, r0, c0, 0,  acc2);
  LOADW(Ur, 64); gemm_tile<HID>(hs, Wb, r0, c0, 64, acc2);

  // r = sigmoid(ar+hr+br); stash own h micro-tile; overwrite hs with r*h
  float hreg[4][4];
  const float4 brv = *(const float4*)&br[c0];
  float rr[4][4];
  #pragma unroll
  for (int r = 0; r < 4; ++r) {
    const float4 hv = *(const float4*)&hs[r0+r][c0];
    hreg[r][0] = hv.x; hreg[r][1] = hv.y; hreg[r][2] = hv.z; hreg[r][3] = hv.w;
    rr[r][0] = sigm(acc2[r][0] + brv.x);
    rr[r][1] = sigm(acc2[r][1] + brv.y);
    rr[r][2] = sigm(acc2[r][2] + brv.z);
    rr[r][3] = sigm(acc2[r][3] + brv.w);
  }
  __syncthreads();
  #pragma unroll
  for (int r = 0; r < 4; ++r) {
    float4 o = make_float4(rr[r][0]*hreg[r][0], rr[r][1]*hreg[r][1],
                           rr[r][2]*hreg[r][2], rr[r][3]*hreg[r][3]);
    *(float4*)&hs[r0+r][c0] = o;
  }
  __syncthreads();
  #pragma unroll
  for (int r = 0; r < 4; ++r)
    #pragma unroll
    for (int c = 0; c < 4; ++c) acc2[r][c] = 0.f;

  LOADW(Wh, 0);  gemm_tile<HID>(as, Wb, r0, c0, 0,  acc2);
  LOADW(Wh, 64); gemm_tile<HID>(as, Wb, r0, c0, 64, acc2);
  LOADW(Uh, 0);  gemm_tile<HID>(hs, Wb, r0, c0, 0,  acc2);   // hs == r*h now
  LOADW(Uh, 64); gemm_tile<HID>(hs, Wb, r0, c0, 64, acc2);

  const float4 bzv = *(const float4*)&bz[c0];
  const float4 bhv = *(const float4*)&bh[c0];
  #pragma unroll
  for (int r = 0; r < 4; ++r) {
    float z0 = sigm(acc1[r][0] + bzv.x), z1 = sigm(acc1[r][1] + bzv.y);
    float z2 = sigm(acc1[r][2] + bzv.z), z3 = sigm(acc1[r][3] + bzv.w);
    float t0 = tanh_fast(acc2[r][0] + bhv.x), t1 = tanh_fast(acc2[r][1] + bhv.y);
    float t2 = tanh_fast(acc2[r][2] + bhv.z), t3 = tanh_fast(acc2[r][3] + bhv.w);
    float4 o;
    o.x = (1.f - z0)*hreg[r][0] + z0*t0;
    o.y = (1.f - z1)*hreg[r][1] + z1*t1;
    o.z = (1.f - z2)*hreg[r][2] + z2*t2;
    o.w = (1.f - z3)*hreg[r][3] + z3*t3;
    *(float4*)&h[(size_t)(row0 + r0 + r)*HID + c0] = o;
  }
}

// positional GRU: s <- (1-zs)s + zs*tanh(h@Wph + (rs*s)@Uph + bph); one wave per row
__global__ __launch_bounds__(256) void k_posgru(const float* __restrict__ h, float* __restrict__ s,
    const float* __restrict__ Wpz, const float* __restrict__ Upz, const float* __restrict__ bpz,
    const float* __restrict__ Wpr, const float* __restrict__ Upr, const float* __restrict__ bpr,
    const float* __restrict__ Wph, const float* __restrict__ Uph, const float* __restrict__ bph) {
  const int lane = threadIdx.x & 63;
  const int w = threadIdx.x >> 6;
  const int row = blockIdx.x * 4 + w;
  const int k0 = lane * 2;
  const float2 hv = *(const float2*)&h[(size_t)row*HID + k0];
  float p[9];
  #pragma unroll
  for (int c = 0; c < 3; ++c) {
    p[c]     = hv.x * Wpz[k0*3 + c] + hv.y * Wpz[(k0+1)*3 + c];
    p[3 + c] = hv.x * Wpr[k0*3 + c] + hv.y * Wpr[(k0+1)*3 + c];
    p[6 + c] = hv.x * Wph[k0*3 + c] + hv.y * Wph[(k0+1)*3 + c];
  }
  #pragma unroll
  for (int off = 32; off > 0; off >>= 1) {
    #pragma unroll
    for (int q = 0; q < 9; ++q) p[q] += __shfl_xor(p[q], off, 64);
  }
  const float s0 = s[(size_t)row*3 + 0], s1 = s[(size_t)row*3 + 1], s2 = s[(size_t)row*3 + 2];
  float zs[3], rs[3], ss[3];
  #pragma unroll
  for (int c = 0; c < 3; ++c) {
    zs[c] = sigm(p[c]     + s0*Upz[c] + s1*Upz[3+c] + s2*Upz[6+c] + bpz[c]);
    rs[c] = sigm(p[3 + c] + s0*Upr[c] + s1*Upr[3+c] + s2*Upr[6+c] + bpr[c]);
  }
  const float t0 = rs[0]*s0, t1 = rs[1]*s1, t2 = rs[2]*s2;
  #pragma unroll
  for (int c = 0; c < 3; ++c)
    ss[c] = tanh_fast(p[6 + c] + t0*Uph[c] + t1*Uph[3+c] + t2*Uph[6+c] + bph[c]);
  if (lane == 0) {
    s[(size_t)row*3 + 0] = (1.f - zs[0])*s0 + zs[0]*ss[0];
    s[(size_t)row*3 + 1] = (1.f - zs[1])*s1 + zs[1]*ss[1];
    s[(size_t)row*3 + 2] = (1.f - zs[2])*s2 + zs[2]*ss[2];
  }
}

// A[b,i,j] = exp(-100*||s_i-s_j||^2)*mask   (16 i-rows per block)
__global__ __launch_bounds__(256) void k_finalA(const float* __restrict__ s, const float* __restrict__ mask,
                                                float* __restrict__ A) {
  __shared__ float sj[NSEQ][3];
  const int t = threadIdx.x;
  const int b = blockIdx.x;
  const int i0 = blockIdx.y * 16;
  {
    const float* sp = s + (size_t)b * NSEQ * 3;
    for (int i = t; i < NSEQ*3; i += 256) (&sj[0][0])[i] = sp[i];
  }
  __syncthreads();
  #pragma unroll
  for (int p = 0; p < 8; ++p) {
    const int e = t + p*256;          // 0..2047
    const int ii = e >> 7;            // 0..15
    const int j4 = (e & 127) * 4;     // 0..508
    const float six = sj[i0+ii][0], siy = sj[i0+ii][1], siz = sj[i0+ii][2];
    const size_t base = ((size_t)b*NSEQ + i0 + ii)*NSEQ + j4;
    const float4 mk = *(const float4*)&mask[base];
    float4 o;
    {
      float dx = six - sj[j4+0][0], dy = siy - sj[j4+0][1], dz = siz - sj[j4+0][2];
      o.x = __expf(-100.0f*(dx*dx + dy*dy + dz*dz)) * mk.x;
    }
    {
      float dx = six - sj[j4+1][0], dy = siy - sj[j4+1][1], dz = siz - sj[j4+1][2];
      o.y = __expf(-100.0f*(dx*dx + dy*dy + dz*dz)) * mk.y;
    }
    {
      float dx = six - sj[j4+2][0], dy = siy - sj[j4+2][1], dz = siz - sj[j4+2][2];
      o.z = __expf(-100.0f*(dx*dx + dy*dy + dz*dz)) * mk.z;
    }
    {
      float dx = six - sj[j4+3][0], dy = siy - sj[j4+3][1], dz = siz - sj[j4+3][2];
      o.w = __expf(-100.0f*(dx*dx + dy*dy + dz*dz)) * mk.w;
    }
    *(float4*)&A[base] = o;
  }
}

// ---------------- launcher ----------------

extern "C" void kernel_launch(void* const* d_in, const int* in_sizes, int n_in,
                              void* d_out, int out_size, void* d_ws, size_t ws_size,
                              hipStream_t stream) {
  const float* x      = (const float*)d_in[0];
  const float* mask   = (const float*)d_in[1];
  const float* W_emb  = (const float*)d_in[2];
  const float* b_emb  = (const float*)d_in[3];
  const float* pos    = (const float*)d_in[4];
  const float* Wm     = (const float*)d_in[5];
  const float* bm     = (const float*)d_in[6];
  const float* Wz     = (const float*)d_in[7];
  const float* Uz     = (const float*)d_in[8];
  const float* bz     = (const float*)d_in[9];
  const float* Wr     = (const float*)d_in[10];
  const float* Ur     = (const float*)d_in[11];
  const float* br     = (const float*)d_in[12];
  const float* Wh     = (const float*)d_in[13];
  const float* Uh     = (const float*)d_in[14];
  const float* bh     = (const float*)d_in[15];
  const float* Wpz    = (const float*)d_in[16];
  const float* Upz    = (const float*)d_in[17];
  const float* bpz    = (const float*)d_in[18];
  const float* Wpr    = (const float*)d_in[19];
  const float* Upr    = (const float*)d_in[20];
  const float* bpr    = (const float*)d_in[21];
  const float* Wph    = (const float*)d_in[22];
  const float* Uph    = (const float*)d_in[23];
  const float* bph    = (const float*)d_in[24];

  float* out = (float*)d_out;
  float* h   = (float*)d_ws;                       // 16 MB
  float* s   = h + (size_t)RTOT * HID;             // 0.4 MB
  float* m   = out;                                // scratch inside d_out (overwritten by k_finalA)
  float* agg = out + (size_t)RTOT * HID;

  k_embed<<<RTOT/32, 256, 0, stream>>>(x, W_emb, b_emb, pos, h);
  k_sinit<<<RTOT/256, 256, 0, stream>>>(s);

  for (int i = 0; i < NITER; ++i) {
    const size_t wo = (size_t)i * HID * HID;
    const size_t bo = (size_t)i * HID;
    k_msg<<<RTOT/32, 256, 0, stream>>>(h, Wm + wo, bm + bo, m);
    k_agg<<<dim3(BSZ, NSEQ/32), 256, 0, stream>>>(s, mask, m, agg);
    k_gru<<<RTOT/32, 256, 0, stream>>>(h, agg,
        Wz + wo, Uz + wo, bz + bo,
        Wr + wo, Ur + wo, br + bo,
        Wh + wo, Uh + wo, bh + bo);
    k_posgru<<<RTOT/4, 256, 0, stream>>>(h, s, Wpz, Upz, bpz, Wpr, Upr, bpr, Wph, Uph, bph);
  }
  k_finalA<<<dim3(BSZ, NSEQ/16), 256, 0, stream>>>(s, mask, out);
}

// Round 3
// 964.502 us; speedup vs baseline: 6.4694x; 6.4694x over previous
//
#include <hip/hip_runtime.h>
#include <math.h>

#define BSZ  64
#define NSEQ 512
#define FEAT 64
#define HID  128
#define NITER 3
#define RTOT (BSZ*NSEQ)   // 32768 rows

// ---------------- helpers ----------------

__device__ __forceinline__ float sigm(float v) {
  v = fminf(fmaxf(v, -30.f), 30.f);
  return 1.0f / (1.0f + __expf(-v));
}
__device__ __forceinline__ float tanh_fast(float v) {
  v = fminf(fmaxf(v, -15.f), 15.f);
  float e = __expf(2.0f * v);
  return (e - 1.0f) / (e + 1.0f);
}

__device__ __forceinline__ void micro4(const float4 a, const float4 b0, const float4 b1,
                                       const float4 b2, const float4 b3, float acc[4]) {
  acc[0] = fmaf(a.x, b0.x, acc[0]); acc[0] = fmaf(a.y, b1.x, acc[0]);
  acc[0] = fmaf(a.z, b2.x, acc[0]); acc[0] = fmaf(a.w, b3.x, acc[0]);
  acc[1] = fmaf(a.x, b0.y, acc[1]); acc[1] = fmaf(a.y, b1.y, acc[1]);
  acc[1] = fmaf(a.z, b2.y, acc[1]); acc[1] = fmaf(a.w, b3.y, acc[1]);
  acc[2] = fmaf(a.x, b0.z, acc[2]); acc[2] = fmaf(a.y, b1.z, acc[2]);
  acc[2] = fmaf(a.z, b2.z, acc[2]); acc[2] = fmaf(a.w, b3.z, acc[2]);
  acc[3] = fmaf(a.x, b0.w, acc[3]); acc[3] = fmaf(a.y, b1.w, acc[3]);
  acc[3] = fmaf(a.z, b2.w, acc[3]); acc[3] = fmaf(a.w, b3.w, acc[3]);
}

// A-tile [*][LDA] (rows broadcast within half-wave), B-tile [*][HID] (float4 over cols)
template<int LDA>
__device__ __forceinline__ void gemm_tile(const float (*At)[LDA], const float (*Bt)[HID],
                                          int r0, int c0, int koff, float acc[4][4]) {
  #pragma unroll
  for (int k = 0; k < 64; k += 4) {
    float4 b0 = *(const float4*)&Bt[k+0][c0];
    float4 b1 = *(const float4*)&Bt[k+1][c0];
    float4 b2 = *(const float4*)&Bt[k+2][c0];
    float4 b3 = *(const float4*)&Bt[k+3][c0];
    float4 a0 = *(const float4*)&At[r0+0][k+koff];
    float4 a1 = *(const float4*)&At[r0+1][k+koff];
    float4 a2 = *(const float4*)&At[r0+2][k+koff];
    float4 a3 = *(const float4*)&At[r0+3][k+koff];
    micro4(a0, b0,b1,b2,b3, acc[0]);
    micro4(a1, b0,b1,b2,b3, acc[1]);
    micro4(a2, b0,b1,b2,b3, acc[2]);
    micro4(a3, b0,b1,b2,b3, acc[3]);
  }
}

// ---------------- kernels ----------------

// h = relu(x @ W_emb + b_emb) + pos_table[:N]   (32 rows/block)
__global__ __launch_bounds__(256) void k_embed(const float* __restrict__ x, const float* __restrict__ W,
                                               const float* __restrict__ bias, const float* __restrict__ pos,
                                               float* __restrict__ h) {
  __shared__ float xs[32][FEAT];    // 8KB
  __shared__ float Ws[FEAT][HID];   // 32KB
  const int t = threadIdx.x;
  const int row0 = blockIdx.x * 32;
  {
    const float4* wv = (const float4*)W;
    float4* wd = (float4*)&Ws[0][0];
    for (int i = t; i < FEAT*HID/4; i += 256) wd[i] = wv[i];
    const float4* xv = (const float4*)(x + (size_t)row0 * FEAT);
    float4* xd = (float4*)&xs[0][0];
    for (int i = t; i < 32*FEAT/4; i += 256) xd[i] = xv[i];
  }
  __syncthreads();
  const int c0 = (t & 31) * 4;
  const int r0 = (t >> 5) * 4;
  float acc[4][4] = {};
  gemm_tile<FEAT>(xs, Ws, r0, c0, 0, acc);
  const float4 bv = *(const float4*)&bias[c0];
  #pragma unroll
  for (int r = 0; r < 4; ++r) {
    const int row = row0 + r0 + r;
    const int n = row & (NSEQ - 1);
    const float4 pv = *(const float4*)&pos[(size_t)n*HID + c0];
    float4 o;
    o.x = fmaxf(acc[r][0] + bv.x, 0.f) + pv.x;
    o.y = fmaxf(acc[r][1] + bv.y, 0.f) + pv.y;
    o.z = fmaxf(acc[r][2] + bv.z, 0.f) + pv.z;
    o.w = fmaxf(acc[r][3] + bv.w, 0.f) + pv.w;
    *(float4*)&h[(size_t)row*HID + c0] = o;
  }
}

// s[b,n] = ((n - (N-1)/2)/N, 0, 0)
__global__ __launch_bounds__(256) void k_sinit(float* __restrict__ s) {
  const int i = blockIdx.x * 256 + threadIdx.x;
  if (i < RTOT) {
    const int n = i & (NSEQ - 1);
    s[(size_t)i*3 + 0] = ((float)n - (NSEQ - 1) * 0.5f) / (float)NSEQ;
    s[(size_t)i*3 + 1] = 0.f;
    s[(size_t)i*3 + 2] = 0.f;
  }
}

// out = relu(in @ W + b)  (32 rows/block, W staged in two 64-row halves)
__global__ __launch_bounds__(256) void k_msg(const float* __restrict__ in, const float* __restrict__ W,
                                             const float* __restrict__ bias, float* __restrict__ out) {
  __shared__ float as[32][HID];   // 16KB
  __shared__ float Wb[64][HID];   // 32KB
  const int t = threadIdx.x;
  const int row0 = blockIdx.x * 32;
  {
    const float4* av = (const float4*)(in + (size_t)row0 * HID);
    float4* ad = (float4*)&as[0][0];
    for (int i = t; i < 32*HID/4; i += 256) ad[i] = av[i];
  }
  const int c0 = (t & 31) * 4;
  const int r0 = (t >> 5) * 4;
  float acc[4][4] = {};
  #pragma unroll 1
  for (int half = 0; half < 2; ++half) {
    __syncthreads();
    const float4* wv = (const float4*)(W + (size_t)half*64*HID);
    float4* wd = (float4*)&Wb[0][0];
    for (int i = t; i < 64*HID/4; i += 256) wd[i] = wv[i];
    __syncthreads();
    gemm_tile<HID>(as, Wb, r0, c0, half*64, acc);
  }
  const float4 bv = *(const float4*)&bias[c0];
  #pragma unroll
  for (int r = 0; r < 4; ++r) {
    float4 o;
    o.x = fmaxf(acc[r][0] + bv.x, 0.f);
    o.y = fmaxf(acc[r][1] + bv.y, 0.f);
    o.z = fmaxf(acc[r][2] + bv.z, 0.f);
    o.w = fmaxf(acc[r][3] + bv.w, 0.f);
    *(float4*)&out[(size_t)(row0 + r0 + r)*HID + c0] = o;
  }
}

// agg[b,i,:] = sum_j exp(-100*||s_i-s_j||^2)*mask[b,i,j]*m[b,j,:]  -- A never materialized
__global__ __launch_bounds__(256) void k_agg(const float* __restrict__ s, const float* __restrict__ mask,
                                             const float* __restrict__ m, float* __restrict__ agg) {
  __shared__ float sj[NSEQ][3];   // 6KB
  __shared__ float ws[32][64];    // 8KB
  __shared__ float ms[64][HID];   // 32KB
  const int t = threadIdx.x;
  const int b = blockIdx.x;
  const int i0 = blockIdx.y * 32;
  {
    const float* sp = s + (size_t)b * NSEQ * 3;
    for (int i = t; i < NSEQ*3; i += 256) (&sj[0][0])[i] = sp[i];
  }
  const int c0 = (t & 31) * 4;
  const int r0 = (t >> 5) * 4;
  float acc[4][4] = {};
  #pragma unroll 1
  for (int j0 = 0; j0 < NSEQ; j0 += 64) {
    __syncthreads();   // covers sj load (first iter) + ws/ms reuse (later iters)
    {
      const float4* mv = (const float4*)(m + ((size_t)b*NSEQ + j0)*HID);
      float4* md = (float4*)&ms[0][0];
      for (int i = t; i < 64*HID/4; i += 256) md[i] = mv[i];
    }
    for (int e = t; e < 32*64; e += 256) {
      const int ii = e >> 6, jj = e & 63;
      const float dx = sj[i0+ii][0] - sj[j0+jj][0];
      const float dy = sj[i0+ii][1] - sj[j0+jj][1];
      const float dz = sj[i0+ii][2] - sj[j0+jj][2];
      const float d2 = dx*dx + dy*dy + dz*dz;
      const float mk = mask[((size_t)b*NSEQ + i0 + ii)*NSEQ + j0 + jj];
      ws[ii][jj] = __expf(-100.0f * d2) * mk;
    }
    __syncthreads();
    gemm_tile<64>(ws, ms, r0, c0, 0, acc);
  }
  #pragma unroll
  for (int r = 0; r < 4; ++r) {
    float4 o = make_float4(acc[r][0], acc[r][1], acc[r][2], acc[r][3]);
    *(float4*)&agg[((size_t)b*NSEQ + i0 + r0 + r)*HID + c0] = o;
  }
}

// ---- GRU split into two small kernels to avoid the VGPR-spill catastrophe ----
// k_zr: z = sigm(agg@Wz + h@Uz + bz); rh = sigm(agg@Wr + h@Ur + br) * h
__global__ __launch_bounds__(256) void k_zr(const float* __restrict__ agg, const float* __restrict__ h,
    const float* __restrict__ Wz, const float* __restrict__ Uz, const float* __restrict__ bz,
    const float* __restrict__ Wr, const float* __restrict__ Ur, const float* __restrict__ br,
    float* __restrict__ zbuf, float* __restrict__ rhbuf) {
  __shared__ float ah[64][HID];   // rows 0-31: agg tile, rows 32-63: h tile  (32KB)
  __shared__ float Wb[64][HID];   // weight k-half staging (32KB) -> 64KB total
  const int t = threadIdx.x;
  const int row0 = blockIdx.x * 32;
  const int c0 = (t & 31) * 4;
  const int r0 = (t >> 5) * 4;
  {
    const float4* av = (const float4*)(agg + (size_t)row0 * HID);
    const float4* hv = (const float4*)(h + (size_t)row0 * HID);
    float4* d = (float4*)&ah[0][0];
    for (int i = t; i < 32*HID/4; i += 256) { d[i] = av[i]; d[i + 32*HID/4] = hv[i]; }
  }
  float accz[4][4] = {};
  float accr[4][4] = {};
  #pragma unroll 1
  for (int g = 0; g < 4; ++g) {
    __syncthreads();
    const float* wsrc = ((g < 2) ? Wz : Uz) + (size_t)(g & 1) * 64 * HID;
    const float4* wv = (const float4*)wsrc;
    float4* wd = (float4*)&Wb[0][0];
    for (int i = t; i < 64*HID/4; i += 256) wd[i] = wv[i];
    __syncthreads();
    gemm_tile<HID>(ah, Wb, ((g < 2) ? 0 : 32) + r0, c0, (g & 1) * 64, accz);
  }
  #pragma unroll 1
  for (int g = 0; g < 4; ++g) {
    __syncthreads();
    const float* wsrc = ((g < 2) ? Wr : Ur) + (size_t)(g & 1) * 64 * HID;
    const float4* wv = (const float4*)wsrc;
    float4* wd = (float4*)&Wb[0][0];
    for (int i = t; i < 64*HID/4; i += 256) wd[i] = wv[i];
    __syncthreads();
    gemm_tile<HID>(ah, Wb, ((g < 2) ? 0 : 32) + r0, c0, (g & 1) * 64, accr);
  }
  const float4 bzv = *(const float4*)&bz[c0];
  const float4 brv = *(const float4*)&br[c0];
  #pragma unroll
  for (int r = 0; r < 4; ++r) {
    const float4 hv4 = *(const float4*)&ah[32 + r0 + r][c0];
    float4 zo, ro;
    zo.x = sigm(accz[r][0] + bzv.x);
    zo.y = sigm(accz[r][1] + bzv.y);
    zo.z = sigm(accz[r][2] + bzv.z);
    zo.w = sigm(accz[r][3] + bzv.w);
    ro.x = sigm(accr[r][0] + brv.x) * hv4.x;
    ro.y = sigm(accr[r][1] + brv.y) * hv4.y;
    ro.z = sigm(accr[r][2] + brv.z) * hv4.z;
    ro.w = sigm(accr[r][3] + brv.w) * hv4.w;
    const size_t o = (size_t)(row0 + r0 + r) * HID + c0;
    *(float4*)&zbuf[o]  = zo;
    *(float4*)&rhbuf[o] = ro;
  }
}

// k_cand: h <- (1-z)*h + z*tanh(agg@Wh + rh@Uh + bh)
__global__ __launch_bounds__(256) void k_cand(const float* __restrict__ agg, const float* __restrict__ rh,
    const float* __restrict__ Wh, const float* __restrict__ Uh, const float* __restrict__ bh,
    const float* __restrict__ zbuf, float* __restrict__ h) {
  __shared__ float ah[64][HID];   // rows 0-31: agg tile, rows 32-63: rh tile
  __shared__ float Wb[64][HID];
  const int t = threadIdx.x;
  const int row0 = blockIdx.x * 32;
  const int c0 = (t & 31) * 4;
  const int r0 = (t >> 5) * 4;
  {
    const float4* av = (const float4*)(agg + (size_t)row0 * HID);
    const float4* rv = (const float4*)(rh + (size_t)row0 * HID);
    float4* d = (float4*)&ah[0][0];
    for (int i = t; i < 32*HID/4; i += 256) { d[i] = av[i]; d[i + 32*HID/4] = rv[i]; }
  }
  float acc[4][4] = {};
  #pragma unroll 1
  for (int g = 0; g < 4; ++g) {
    __syncthreads();
    const float* wsrc = ((g < 2) ? Wh : Uh) + (size_t)(g & 1) * 64 * HID;
    const float4* wv = (const float4*)wsrc;
    float4* wd = (float4*)&Wb[0][0];
    for (int i = t; i < 64*HID/4; i += 256) wd[i] = wv[i];
    __syncthreads();
    gemm_tile<HID>(ah, Wb, ((g < 2) ? 0 : 32) + r0, c0, (g & 1) * 64, acc);
  }
  const float4 bhv = *(const float4*)&bh[c0];
  #pragma unroll
  for (int r = 0; r < 4; ++r) {
    const size_t o = (size_t)(row0 + r0 + r) * HID + c0;
    const float4 zv = *(const float4*)&zbuf[o];
    const float4 hv = *(const float4*)&h[o];
    float4 res;
    res.x = (1.f - zv.x) * hv.x + zv.x * tanh_fast(acc[r][0] + bhv.x);
    res.y = (1.f - zv.y) * hv.y + zv.y * tanh_fast(acc[r][1] + bhv.y);
    res.z = (1.f - zv.z) * hv.z + zv.z * tanh_fast(acc[r][2] + bhv.z);
    res.w = (1.f - zv.w) * hv.w + zv.w * tanh_fast(acc[r][3] + bhv.w);
    *(float4*)&h[o] = res;
  }
}

// positional GRU: s <- (1-zs)s + zs*tanh(h@Wph + (rs*s)@Uph + bph); one wave per row
__global__ __launch_bounds__(256) void k_posgru(const float* __restrict__ h, float* __restrict__ s,
    const float* __restrict__ Wpz, const float* __restrict__ Upz, const float* __restrict__ bpz,
    const float* __restrict__ Wpr, const float* __restrict__ Upr, const float* __restrict__ bpr,
    const float* __restrict__ Wph, const float* __restrict__ Uph, const float* __restrict__ bph) {
  const int lane = threadIdx.x & 63;
  const int w = threadIdx.x >> 6;
  const int row = blockIdx.x * 4 + w;
  const int k0 = lane * 2;
  const float2 hv = *(const float2*)&h[(size_t)row*HID + k0];
  float p[9];
  #pragma unroll
  for (int c = 0; c < 3; ++c) {
    p[c]     = hv.x * Wpz[k0*3 + c] + hv.y * Wpz[(k0+1)*3 + c];
    p[3 + c] = hv.x * Wpr[k0*3 + c] + hv.y * Wpr[(k0+1)*3 + c];
    p[6 + c] = hv.x * Wph[k0*3 + c] + hv.y * Wph[(k0+1)*3 + c];
  }
  #pragma unroll
  for (int off = 32; off > 0; off >>= 1) {
    #pragma unroll
    for (int q = 0; q < 9; ++q) p[q] += __shfl_xor(p[q], off, 64);
  }
  const float s0 = s[(size_t)row*3 + 0], s1 = s[(size_t)row*3 + 1], s2 = s[(size_t)row*3 + 2];
  float zs[3], rs[3], ss[3];
  #pragma unroll
  for (int c = 0; c < 3; ++c) {
    zs[c] = sigm(p[c]     + s0*Upz[c] + s1*Upz[3+c] + s2*Upz[6+c] + bpz[c]);
    rs[c] = sigm(p[3 + c] + s0*Upr[c] + s1*Upr[3+c] + s2*Upr[6+c] + bpr[c]);
  }
  const float t0 = rs[0]*s0, t1 = rs[1]*s1, t2 = rs[2]*s2;
  #pragma unroll
  for (int c = 0; c < 3; ++c)
    ss[c] = tanh_fast(p[6 + c] + t0*Uph[c] + t1*Uph[3+c] + t2*Uph[6+c] + bph[c]);
  if (lane == 0) {
    s[(size_t)row*3 + 0] = (1.f - zs[0])*s0 + zs[0]*ss[0];
    s[(size_t)row*3 + 1] = (1.f - zs[1])*s1 + zs[1]*ss[1];
    s[(size_t)row*3 + 2] = (1.f - zs[2])*s2 + zs[2]*ss[2];
  }
}

// A[b,i,j] = exp(-100*||s_i-s_j||^2)*mask   (16 i-rows per block)
__global__ __launch_bounds__(256) void k_finalA(const float* __restrict__ s, const float* __restrict__ mask,
                                                float* __restrict__ A) {
  __shared__ float sj[NSEQ][3];
  const int t = threadIdx.x;
  const int b = blockIdx.x;
  const int i0 = blockIdx.y * 16;
  {
    const float* sp = s + (size_t)b * NSEQ * 3;
    for (int i = t; i < NSEQ*3; i += 256) (&sj[0][0])[i] = sp[i];
  }
  __syncthreads();
  #pragma unroll
  for (int p = 0; p < 8; ++p) {
    const int e = t + p*256;          // 0..2047
    const int ii = e >> 7;            // 0..15
    const int j4 = (e & 127) * 4;     // 0..508
    const float six = sj[i0+ii][0], siy = sj[i0+ii][1], siz = sj[i0+ii][2];
    const size_t base = ((size_t)b*NSEQ + i0 + ii)*NSEQ + j4;
    const float4 mk = *(const float4*)&mask[base];
    float4 o;
    {
      float dx = six - sj[j4+0][0], dy = siy - sj[j4+0][1], dz = siz - sj[j4+0][2];
      o.x = __expf(-100.0f*(dx*dx + dy*dy + dz*dz)) * mk.x;
    }
    {
      float dx = six - sj[j4+1][0], dy = siy - sj[j4+1][1], dz = siz - sj[j4+1][2];
      o.y = __expf(-100.0f*(dx*dx + dy*dy + dz*dz)) * mk.y;
    }
    {
      float dx = six - sj[j4+2][0], dy = siy - sj[j4+2][1], dz = siz - sj[j4+2][2];
      o.z = __expf(-100.0f*(dx*dx + dy*dy + dz*dz)) * mk.z;
    }
    {
      float dx = six - sj[j4+3][0], dy = siy - sj[j4+3][1], dz = siz - sj[j4+3][2];
      o.w = __expf(-100.0f*(dx*dx + dy*dy + dz*dz)) * mk.w;
    }
    *(float4*)&A[base] = o;
  }
}

// ---------------- launcher ----------------

extern "C" void kernel_launch(void* const* d_in, const int* in_sizes, int n_in,
                              void* d_out, int out_size, void* d_ws, size_t ws_size,
                              hipStream_t stream) {
  const float* x      = (const float*)d_in[0];
  const float* mask   = (const float*)d_in[1];
  const float* W_emb  = (const float*)d_in[2];
  const float* b_emb  = (const float*)d_in[3];
  const float* pos    = (const float*)d_in[4];
  const float* Wm     = (const float*)d_in[5];
  const float* bm     = (const float*)d_in[6];
  const float* Wz     = (const float*)d_in[7];
  const float* Uz     = (const float*)d_in[8];
  const float* bz     = (const float*)d_in[9];
  const float* Wr     = (const float*)d_in[10];
  const float* Ur     = (const float*)d_in[11];
  const float* br     = (const float*)d_in[12];
  const float* Wh     = (const float*)d_in[13];
  const float* Uh     = (const float*)d_in[14];
  const float* bh     = (const float*)d_in[15];
  const float* Wpz    = (const float*)d_in[16];
  const float* Upz    = (const float*)d_in[17];
  const float* bpz    = (const float*)d_in[18];
  const float* Wpr    = (const float*)d_in[19];
  const float* Upr    = (const float*)d_in[20];
  const float* bpr    = (const float*)d_in[21];
  const float* Wph    = (const float*)d_in[22];
  const float* Uph    = (const float*)d_in[23];
  const float* bph    = (const float*)d_in[24];

  float* out = (float*)d_out;
  float* h   = (float*)d_ws;                       // 16 MB
  float* s   = h + (size_t)RTOT * HID;             // 0.4 MB
  // d_out is exactly 4 * RTOT*HID floats; all four scratch views are dead
  // before k_finalA overwrites the full output.
  float* m   = out;                                // [0, 4M)
  float* agg = out + (size_t)RTOT * HID;           // [4M, 8M)
  float* zb  = out + (size_t)2 * RTOT * HID;       // [8M, 12M)
  float* rhb = out + (size_t)3 * RTOT * HID;       // [12M, 16M)

  k_embed<<<RTOT/32, 256, 0, stream>>>(x, W_emb, b_emb, pos, h);
  k_sinit<<<RTOT/256, 256, 0, stream>>>(s);

  for (int i = 0; i < NITER; ++i) {
    const size_t wo = (size_t)i * HID * HID;
    const size_t bo = (size_t)i * HID;
    k_msg<<<RTOT/32, 256, 0, stream>>>(h, Wm + wo, bm + bo, m);
    k_agg<<<dim3(BSZ, NSEQ/32), 256, 0, stream>>>(s, mask, m, agg);
    k_zr<<<RTOT/32, 256, 0, stream>>>(agg, h,
        Wz + wo, Uz + wo, bz + bo,
        Wr + wo, Ur + wo, br + bo, zb, rhb);
    k_cand<<<RTOT/32, 256, 0, stream>>>(agg, rhb,
        Wh + wo, Uh + wo, bh + bo, zb, h);
    k_posgru<<<RTOT/4, 256, 0, stream>>>(h, s, Wpz, Upz, bpz, Wpr, Upr, bpr, Wph, Uph, bph);
  }
  k_finalA<<<dim3(BSZ, NSEQ/16), 256, 0, stream>>>(s, mask, out);
}

// Round 4
// 893.890 us; speedup vs baseline: 6.9805x; 1.0790x over previous
//
#include <hip/hip_runtime.h>
#include <math.h>

#define BSZ  64
#define NSEQ 512
#define FEAT 64
#define HID  128
#define NITER 3
#define RTOT (BSZ*NSEQ)   // 32768 rows

// ---------------- helpers ----------------

__device__ __forceinline__ float sigm(float v) {
  v = fminf(fmaxf(v, -30.f), 30.f);
  return 1.0f / (1.0f + __expf(-v));
}
__device__ __forceinline__ float tanh_fast(float v) {
  v = fminf(fmaxf(v, -15.f), 15.f);
  float e = __expf(2.0f * v);
  return (e - 1.0f) / (e + 1.0f);
}

__device__ __forceinline__ void micro4(const float4 a, const float4 b0, const float4 b1,
                                       const float4 b2, const float4 b3, float acc[4]) {
  acc[0] = fmaf(a.x, b0.x, acc[0]); acc[0] = fmaf(a.y, b1.x, acc[0]);
  acc[0] = fmaf(a.z, b2.x, acc[0]); acc[0] = fmaf(a.w, b3.x, acc[0]);
  acc[1] = fmaf(a.x, b0.y, acc[1]); acc[1] = fmaf(a.y, b1.y, acc[1]);
  acc[1] = fmaf(a.z, b2.y, acc[1]); acc[1] = fmaf(a.w, b3.y, acc[1]);
  acc[2] = fmaf(a.x, b0.z, acc[2]); acc[2] = fmaf(a.y, b1.z, acc[2]);
  acc[2] = fmaf(a.z, b2.z, acc[2]); acc[2] = fmaf(a.w, b3.z, acc[2]);
  acc[3] = fmaf(a.x, b0.w, acc[3]); acc[3] = fmaf(a.y, b1.w, acc[3]);
  acc[3] = fmaf(a.z, b2.w, acc[3]); acc[3] = fmaf(a.w, b3.w, acc[3]);
}

// A-tile from LDS (rows ra..ra+3, broadcast within half-wave), B read directly
// from GLOBAL (row-major, stride HID; identical addresses for lanes l and l+32
// -> L1/L2 broadcast). Removes all B-staging barriers.
template<int LDA, int KTOT>
__device__ __forceinline__ void gemm_gb(const float (*At)[LDA], int ra,
                                        const float* __restrict__ Bg,
                                        int c0, float acc[4][4]) {
  #pragma unroll 2
  for (int k = 0; k < KTOT; k += 4) {
    float4 b0 = *(const float4*)&Bg[(k+0)*HID + c0];
    float4 b1 = *(const float4*)&Bg[(k+1)*HID + c0];
    float4 b2 = *(const float4*)&Bg[(k+2)*HID + c0];
    float4 b3 = *(const float4*)&Bg[(k+3)*HID + c0];
    float4 a0 = *(const float4*)&At[ra+0][k];
    float4 a1 = *(const float4*)&At[ra+1][k];
    float4 a2 = *(const float4*)&At[ra+2][k];
    float4 a3 = *(const float4*)&At[ra+3][k];
    micro4(a0, b0,b1,b2,b3, acc[0]);
    micro4(a1, b0,b1,b2,b3, acc[1]);
    micro4(a2, b0,b1,b2,b3, acc[2]);
    micro4(a3, b0,b1,b2,b3, acc[3]);
  }
}

// ---------------- kernels ----------------

// h = relu(x @ W_emb + b_emb) + pos_table[:n]; W_emb read from global
__global__ __launch_bounds__(256) void k_embed(const float* __restrict__ x, const float* __restrict__ W,
                                               const float* __restrict__ bias, const float* __restrict__ pos,
                                               float* __restrict__ h) {
  __shared__ float xs[32][FEAT];    // 8KB
  const int t = threadIdx.x;
  const int row0 = blockIdx.x * 32;
  {
    const float4* xv = (const float4*)(x + (size_t)row0 * FEAT);
    float4* xd = (float4*)&xs[0][0];
    for (int i = t; i < 32*FEAT/4; i += 256) xd[i] = xv[i];
  }
  __syncthreads();
  const int c0 = (t & 31) * 4;
  const int r0 = (t >> 5) * 4;
  float acc[4][4] = {};
  gemm_gb<FEAT, FEAT>(xs, r0, W, c0, acc);
  const float4 bv = *(const float4*)&bias[c0];
  #pragma unroll
  for (int r = 0; r < 4; ++r) {
    const int row = row0 + r0 + r;
    const int n = row & (NSEQ - 1);
    const float4 pv = *(const float4*)&pos[(size_t)n*HID + c0];
    float4 o;
    o.x = fmaxf(acc[r][0] + bv.x, 0.f) + pv.x;
    o.y = fmaxf(acc[r][1] + bv.y, 0.f) + pv.y;
    o.z = fmaxf(acc[r][2] + bv.z, 0.f) + pv.z;
    o.w = fmaxf(acc[r][3] + bv.w, 0.f) + pv.w;
    *(float4*)&h[(size_t)row*HID + c0] = o;
  }
}

// s[b,n] = ((n - (N-1)/2)/N, 0, 0)
__global__ __launch_bounds__(256) void k_sinit(float* __restrict__ s) {
  const int i = blockIdx.x * 256 + threadIdx.x;
  if (i < RTOT) {
    const int n = i & (NSEQ - 1);
    s[(size_t)i*3 + 0] = ((float)n - (NSEQ - 1) * 0.5f) / (float)NSEQ;
    s[(size_t)i*3 + 1] = 0.f;
    s[(size_t)i*3 + 2] = 0.f;
  }
}

// out = relu(in @ W + b); W from global, one barrier total
__global__ __launch_bounds__(256) void k_msg(const float* __restrict__ in, const float* __restrict__ W,
                                             const float* __restrict__ bias, float* __restrict__ out) {
  __shared__ float as[32][HID];   // 16KB
  const int t = threadIdx.x;
  const int row0 = blockIdx.x * 32;
  {
    const float4* av = (const float4*)(in + (size_t)row0 * HID);
    float4* ad = (float4*)&as[0][0];
    for (int i = t; i < 32*HID/4; i += 256) ad[i] = av[i];
  }
  __syncthreads();
  const int c0 = (t & 31) * 4;
  const int r0 = (t >> 5) * 4;
  float acc[4][4] = {};
  gemm_gb<HID, HID>(as, r0, W, c0, acc);
  const float4 bv = *(const float4*)&bias[c0];
  #pragma unroll
  for (int r = 0; r < 4; ++r) {
    float4 o;
    o.x = fmaxf(acc[r][0] + bv.x, 0.f);
    o.y = fmaxf(acc[r][1] + bv.y, 0.f);
    o.z = fmaxf(acc[r][2] + bv.z, 0.f);
    o.w = fmaxf(acc[r][3] + bv.w, 0.f);
    *(float4*)&out[(size_t)(row0 + r0 + r)*HID + c0] = o;
  }
}

// agg[b,i,:] = sum_j exp(-100*||s_i-s_j||^2)*mask[b,i,j]*m[b,j,:]
// ws double-buffered (1 barrier/tile); m read from global (L1/L2-hot);
// next tile's mask loads issued BEFORE the gemm so HBM latency hides under FMAs.
__global__ __launch_bounds__(256) void k_agg(const float* __restrict__ s, const float* __restrict__ mask,
                                             const float* __restrict__ m, float* __restrict__ agg) {
  __shared__ float sj[NSEQ][3];     // 6KB
  __shared__ float ws[2][32][64];   // 16KB double-buffered
  const int t = threadIdx.x;
  const int b = blockIdx.x;
  const int i0 = blockIdx.y * 32;
  {
    const float* sp = s + (size_t)b * NSEQ * 3;
    for (int i = t; i < NSEQ*3; i += 256) (&sj[0][0])[i] = sp[i];
  }
  __syncthreads();
  const float* maskb = mask + (size_t)b * NSEQ * NSEQ;
  // tile 0 into ws[0]
  #pragma unroll
  for (int p = 0; p < 8; ++p) {
    const int e = t + p*256, wi = e >> 6, wj = e & 63;
    const float dx = sj[i0+wi][0] - sj[wj][0];
    const float dy = sj[i0+wi][1] - sj[wj][1];
    const float dz = sj[i0+wi][2] - sj[wj][2];
    const float mk = maskb[(size_t)(i0+wi)*NSEQ + wj];
    ws[0][wi][wj] = __expf(-100.0f*(dx*dx + dy*dy + dz*dz)) * mk;
  }
  __syncthreads();
  const int c0 = (t & 31) * 4;
  const int r0 = (t >> 5) * 4;
  float acc[4][4] = {};
  const float* mb = m + (size_t)b * NSEQ * HID;
  #pragma unroll 1
  for (int jt = 0; jt < 8; ++jt) {
    const int buf = jt & 1;
    float mk[8];
    if (jt < 7) {   // issue next tile's mask loads early (latency under gemm)
      const int j0n = (jt+1) * 64;
      #pragma unroll
      for (int p = 0; p < 8; ++p) {
        const int e = t + p*256, wi = e >> 6, wj = e & 63;
        mk[p] = maskb[(size_t)(i0+wi)*NSEQ + j0n + wj];
      }
    }
    gemm_gb<64, 64>(ws[buf], r0, mb + (size_t)jt*64*HID, c0, acc);
    if (jt < 7) {
      const int j0n = (jt+1) * 64;
      #pragma unroll
      for (int p = 0; p < 8; ++p) {
        const int e = t + p*256, wi = e >> 6, wj = e & 63;
        const float dx = sj[i0+wi][0] - sj[j0n+wj][0];
        const float dy = sj[i0+wi][1] - sj[j0n+wj][1];
        const float dz = sj[i0+wi][2] - sj[j0n+wj][2];
        ws[buf^1][wi][wj] = __expf(-100.0f*(dx*dx + dy*dy + dz*dz)) * mk[p];
      }
    }
    __syncthreads();
  }
  #pragma unroll
  for (int r = 0; r < 4; ++r) {
    float4 o = make_float4(acc[r][0], acc[r][1], acc[r][2], acc[r][3]);
    *(float4*)&agg[((size_t)b*NSEQ + i0 + r0 + r)*HID + c0] = o;
  }
}

// k_zr: z = sigm(agg@Wz + h@Uz + bz); rh = sigm(agg@Wr + h@Ur + br) * h
// Weights streamed from global (identical across blocks); ONE barrier.
__global__ __launch_bounds__(256) void k_zr(const float* __restrict__ agg, const float* __restrict__ h,
    const float* __restrict__ Wz, const float* __restrict__ Uz, const float* __restrict__ bz,
    const float* __restrict__ Wr, const float* __restrict__ Ur, const float* __restrict__ br,
    float* __restrict__ zbuf, float* __restrict__ rhbuf) {
  __shared__ float ah[64][HID];   // rows 0-31: agg tile, rows 32-63: h tile (32KB)
  const int t = threadIdx.x;
  const int row0 = blockIdx.x * 32;
  const int c0 = (t & 31) * 4;
  const int r0 = (t >> 5) * 4;
  {
    const float4* av = (const float4*)(agg + (size_t)row0 * HID);
    const float4* hv = (const float4*)(h + (size_t)row0 * HID);
    float4* d = (float4*)&ah[0][0];
    for (int i = t; i < 32*HID/4; i += 256) { d[i] = av[i]; d[i + 32*HID/4] = hv[i]; }
  }
  __syncthreads();
  float accz[4][4] = {};
  float accr[4][4] = {};
  gemm_gb<HID, HID>(ah, r0,      Wz, c0, accz);
  gemm_gb<HID, HID>(ah, 32 + r0, Uz, c0, accz);
  gemm_gb<HID, HID>(ah, r0,      Wr, c0, accr);
  gemm_gb<HID, HID>(ah, 32 + r0, Ur, c0, accr);
  const float4 bzv = *(const float4*)&bz[c0];
  const float4 brv = *(const float4*)&br[c0];
  #pragma unroll
  for (int r = 0; r < 4; ++r) {
    const float4 hv4 = *(const float4*)&ah[32 + r0 + r][c0];
    float4 zo, ro;
    zo.x = sigm(accz[r][0] + bzv.x);
    zo.y = sigm(accz[r][1] + bzv.y);
    zo.z = sigm(accz[r][2] + bzv.z);
    zo.w = sigm(accz[r][3] + bzv.w);
    ro.x = sigm(accr[r][0] + brv.x) * hv4.x;
    ro.y = sigm(accr[r][1] + brv.y) * hv4.y;
    ro.z = sigm(accr[r][2] + brv.z) * hv4.z;
    ro.w = sigm(accr[r][3] + brv.w) * hv4.w;
    const size_t o = (size_t)(row0 + r0 + r) * HID + c0;
    *(float4*)&zbuf[o]  = zo;
    *(float4*)&rhbuf[o] = ro;
  }
}

// k_cand: h <- (1-z)*h + z*tanh(agg@Wh + rh@Uh + bh); ONE barrier.
__global__ __launch_bounds__(256) void k_cand(const float* __restrict__ agg, const float* __restrict__ rh,
    const float* __restrict__ Wh, const float* __restrict__ Uh, const float* __restrict__ bh,
    const float* __restrict__ zbuf, float* __restrict__ h) {
  __shared__ float ah[64][HID];   // rows 0-31: agg, rows 32-63: rh
  const int t = threadIdx.x;
  const int row0 = blockIdx.x * 32;
  const int c0 = (t & 31) * 4;
  const int r0 = (t >> 5) * 4;
  {
    const float4* av = (const float4*)(agg + (size_t)row0 * HID);
    const float4* rv = (const float4*)(rh + (size_t)row0 * HID);
    float4* d = (float4*)&ah[0][0];
    for (int i = t; i < 32*HID/4; i += 256) { d[i] = av[i]; d[i + 32*HID/4] = rv[i]; }
  }
  __syncthreads();
  float acc[4][4] = {};
  gemm_gb<HID, HID>(ah, r0,      Wh, c0, acc);
  gemm_gb<HID, HID>(ah, 32 + r0, Uh, c0, acc);
  const float4 bhv = *(const float4*)&bh[c0];
  #pragma unroll
  for (int r = 0; r < 4; ++r) {
    const size_t o = (size_t)(row0 + r0 + r) * HID + c0;
    const float4 zv = *(const float4*)&zbuf[o];
    const float4 hv = *(const float4*)&h[o];
    float4 res;
    res.x = (1.f - zv.x) * hv.x + zv.x * tanh_fast(acc[r][0] + bhv.x);
    res.y = (1.f - zv.y) * hv.y + zv.y * tanh_fast(acc[r][1] + bhv.y);
    res.z = (1.f - zv.z) * hv.z + zv.z * tanh_fast(acc[r][2] + bhv.z);
    res.w = (1.f - zv.w) * hv.w + zv.w * tanh_fast(acc[r][3] + bhv.w);
    *(float4*)&h[o] = res;
  }
}

// positional GRU: s <- (1-zs)s + zs*tanh(h@Wph + (rs*s)@Uph + bph); one wave per row
__global__ __launch_bounds__(256) void k_posgru(const float* __restrict__ h, float* __restrict__ s,
    const float* __restrict__ Wpz, const float* __restrict__ Upz, const float* __restrict__ bpz,
    const float* __restrict__ Wpr, const float* __restrict__ Upr, const float* __restrict__ bpr,
    const float* __restrict__ Wph, const float* __restrict__ Uph, const float* __restrict__ bph) {
  const int lane = threadIdx.x & 63;
  const int w = threadIdx.x >> 6;
  const int row = blockIdx.x * 4 + w;
  const int k0 = lane * 2;
  const float2 hv = *(const float2*)&h[(size_t)row*HID + k0];
  float p[9];
  #pragma unroll
  for (int c = 0; c < 3; ++c) {
    p[c]     = hv.x * Wpz[k0*3 + c] + hv.y * Wpz[(k0+1)*3 + c];
    p[3 + c] = hv.x * Wpr[k0*3 + c] + hv.y * Wpr[(k0+1)*3 + c];
    p[6 + c] = hv.x * Wph[k0*3 + c] + hv.y * Wph[(k0+1)*3 + c];
  }
  #pragma unroll
  for (int off = 32; off > 0; off >>= 1) {
    #pragma unroll
    for (int q = 0; q < 9; ++q) p[q] += __shfl_xor(p[q], off, 64);
  }
  const float s0 = s[(size_t)row*3 + 0], s1 = s[(size_t)row*3 + 1], s2 = s[(size_t)row*3 + 2];
  float zs[3], rs[3], ss[3];
  #pragma unroll
  for (int c = 0; c < 3; ++c) {
    zs[c] = sigm(p[c]     + s0*Upz[c] + s1*Upz[3+c] + s2*Upz[6+c] + bpz[c]);
    rs[c] = sigm(p[3 + c] + s0*Upr[c] + s1*Upr[3+c] + s2*Upr[6+c] + bpr[c]);
  }
  const float t0 = rs[0]*s0, t1 = rs[1]*s1, t2 = rs[2]*s2;
  #pragma unroll
  for (int c = 0; c < 3; ++c)
    ss[c] = tanh_fast(p[6 + c] + t0*Uph[c] + t1*Uph[3+c] + t2*Uph[6+c] + bph[c]);
  if (lane == 0) {
    s[(size_t)row*3 + 0] = (1.f - zs[0])*s0 + zs[0]*ss[0];
    s[(size_t)row*3 + 1] = (1.f - zs[1])*s1 + zs[1]*ss[1];
    s[(size_t)row*3 + 2] = (1.f - zs[2])*s2 + zs[2]*ss[2];
  }
}

// A[b,i,j] = exp(-100*||s_i-s_j||^2)*mask   (16 i-rows per block)
__global__ __launch_bounds__(256) void k_finalA(const float* __restrict__ s, const float* __restrict__ mask,
                                                float* __restrict__ A) {
  __shared__ float sj[NSEQ][3];
  const int t = threadIdx.x;
  const int b = blockIdx.x;
  const int i0 = blockIdx.y * 16;
  {
    const float* sp = s + (size_t)b * NSEQ * 3;
    for (int i = t; i < NSEQ*3; i += 256) (&sj[0][0])[i] = sp[i];
  }
  __syncthreads();
  #pragma unroll
  for (int p = 0; p < 8; ++p) {
    const int e = t + p*256;          // 0..2047
    const int ii = e >> 7;            // 0..15
    const int j4 = (e & 127) * 4;     // 0..508
    const float six = sj[i0+ii][0], siy = sj[i0+ii][1], siz = sj[i0+ii][2];
    const size_t base = ((size_t)b*NSEQ + i0 + ii)*NSEQ + j4;
    const float4 mk = *(const float4*)&mask[base];
    float4 o;
    {
      float dx = six - sj[j4+0][0], dy = siy - sj[j4+0][1], dz = siz - sj[j4+0][2];
      o.x = __expf(-100.0f*(dx*dx + dy*dy + dz*dz)) * mk.x;
    }
    {
      float dx = six - sj[j4+1][0], dy = siy - sj[j4+1][1], dz = siz - sj[j4+1][2];
      o.y = __expf(-100.0f*(dx*dx + dy*dy + dz*dz)) * mk.y;
    }
    {
      float dx = six - sj[j4+2][0], dy = siy - sj[j4+2][1], dz = siz - sj[j4+2][2];
      o.z = __expf(-100.0f*(dx*dx + dy*dy + dz*dz)) * mk.z;
    }
    {
      float dx = six - sj[j4+3][0], dy = siy - sj[j4+3][1], dz = siz - sj[j4+3][2];
      o.w = __expf(-100.0f*(dx*dx + dy*dy + dz*dz)) * mk.w;
    }
    *(float4*)&A[base] = o;
  }
}

// ---------------- launcher ----------------

extern "C" void kernel_launch(void* const* d_in, const int* in_sizes, int n_in,
                              void* d_out, int out_size, void* d_ws, size_t ws_size,
                              hipStream_t stream) {
  const float* x      = (const float*)d_in[0];
  const float* mask   = (const float*)d_in[1];
  const float* W_emb  = (const float*)d_in[2];
  const float* b_emb  = (const float*)d_in[3];
  const float* pos    = (const float*)d_in[4];
  const float* Wm     = (const float*)d_in[5];
  const float* bm     = (const float*)d_in[6];
  const float* Wz     = (const float*)d_in[7];
  const float* Uz     = (const float*)d_in[8];
  const float* bz     = (const float*)d_in[9];
  const float* Wr     = (const float*)d_in[10];
  const float* Ur     = (const float*)d_in[11];
  const float* br     = (const float*)d_in[12];
  const float* Wh     = (const float*)d_in[13];
  const float* Uh     = (const float*)d_in[14];
  const float* bh     = (const float*)d_in[15];
  const float* Wpz    = (const float*)d_in[16];
  const float* Upz    = (const float*)d_in[17];
  const float* bpz    = (const float*)d_in[18];
  const float* Wpr    = (const float*)d_in[19];
  const float* Upr    = (const float*)d_in[20];
  const float* bpr    = (const float*)d_in[21];
  const float* Wph    = (const float*)d_in[22];
  const float* Uph    = (const float*)d_in[23];
  const float* bph    = (const float*)d_in[24];

  float* out = (float*)d_out;
  float* h   = (float*)d_ws;                       // 16 MB
  float* s   = h + (size_t)RTOT * HID;             // 0.4 MB
  // d_out is exactly 4 * RTOT*HID floats; all four scratch views are dead
  // before k_finalA overwrites the full output.
  float* m   = out;                                // [0, 4M)
  float* agg = out + (size_t)RTOT * HID;           // [4M, 8M)
  float* zb  = out + (size_t)2 * RTOT * HID;       // [8M, 12M)
  float* rhb = out + (size_t)3 * RTOT * HID;       // [12M, 16M)

  k_embed<<<RTOT/32, 256, 0, stream>>>(x, W_emb, b_emb, pos, h);
  k_sinit<<<RTOT/256, 256, 0, stream>>>(s);

  for (int i = 0; i < NITER; ++i) {
    const size_t wo = (size_t)i * HID * HID;
    const size_t bo = (size_t)i * HID;
    k_msg<<<RTOT/32, 256, 0, stream>>>(h, Wm + wo, bm + bo, m);
    k_agg<<<dim3(BSZ, NSEQ/32), 256, 0, stream>>>(s, mask, m, agg);
    k_zr<<<RTOT/32, 256, 0, stream>>>(agg, h,
        Wz + wo, Uz + wo, bz + bo,
        Wr + wo, Ur + wo, br + bo, zb, rhb);
    k_cand<<<RTOT/32, 256, 0, stream>>>(agg, rhb,
        Wh + wo, Uh + wo, bh + bo, zb, h);
    k_posgru<<<RTOT/4, 256, 0, stream>>>(h, s, Wpz, Upz, bpz, Wpr, Upr, bpr, Wph, Uph, bph);
  }
  k_finalA<<<dim3(BSZ, NSEQ/16), 256, 0, stream>>>(s, mask, out);
}

// Round 5
// 862.119 us; speedup vs baseline: 7.2377x; 1.0369x over previous
//
#include <hip/hip_runtime.h>
#include <math.h>

#define BSZ  64
#define NSEQ 512
#define FEAT 64
#define HID  128
#define NITER 3
#define RTOT (BSZ*NSEQ)   // 32768 rows

typedef const __attribute__((address_space(1))) void* gptr_as1;
typedef __attribute__((address_space(3))) void* lptr_as3;

// ---------------- helpers ----------------

__device__ __forceinline__ float sigm(float v) {
  v = fminf(fmaxf(v, -30.f), 30.f);
  return 1.0f / (1.0f + __expf(-v));
}
__device__ __forceinline__ float tanh_fast(float v) {
  v = fminf(fmaxf(v, -15.f), 15.f);
  float e = __expf(2.0f * v);
  return (e - 1.0f) / (e + 1.0f);
}

// Async-stage one 32-row x 128-col fp32 slab (16 KB, contiguous in global)
// into LDS via global_load_lds width-16. LDS dest is wave-uniform base +
// lane*16 (HW rule), so LDS layout must be linear == global layout (it is).
__device__ __forceinline__ void stage_slab(const float* __restrict__ g, float* l, int t) {
  const int w = t >> 6, lane = t & 63;
  #pragma unroll
  for (int i = 0; i < 4; ++i) {
    const int c = i * 4 + w;   // 1KB chunk 0..15
    __builtin_amdgcn_global_load_lds((gptr_as1)(g + c * 256 + lane * 4),
                                     (lptr_as3)(l + c * 256), 16, 0, 0);
  }
}

__device__ __forceinline__ void micro4(const float4 a, const float4 b0, const float4 b1,
                                       const float4 b2, const float4 b3, float acc[4]) {
  acc[0] = fmaf(a.x, b0.x, acc[0]); acc[0] = fmaf(a.y, b1.x, acc[0]);
  acc[0] = fmaf(a.z, b2.x, acc[0]); acc[0] = fmaf(a.w, b3.x, acc[0]);
  acc[1] = fmaf(a.x, b0.y, acc[1]); acc[1] = fmaf(a.y, b1.y, acc[1]);
  acc[1] = fmaf(a.z, b2.y, acc[1]); acc[1] = fmaf(a.w, b3.y, acc[1]);
  acc[2] = fmaf(a.x, b0.z, acc[2]); acc[2] = fmaf(a.y, b1.z, acc[2]);
  acc[2] = fmaf(a.z, b2.z, acc[2]); acc[2] = fmaf(a.w, b3.z, acc[2]);
  acc[3] = fmaf(a.x, b0.w, acc[3]); acc[3] = fmaf(a.y, b1.w, acc[3]);
  acc[3] = fmaf(a.z, b2.w, acc[3]); acc[3] = fmaf(a.w, b3.w, acc[3]);
}

// 32-deep K-slab GEMM: A rows ra..ra+3 from LDS (cols koff..koff+31),
// B slab [32][HID] from LDS, 4x4 acc at (ra, c0).
template<int LDA>
__device__ __forceinline__ void gemm_slab(const float (*At)[LDA], int ra, int koff,
                                          const float (*Bt)[HID], int c0, float acc[4][4]) {
  #pragma unroll 2
  for (int k = 0; k < 32; k += 4) {
    float4 b0 = *(const float4*)&Bt[k+0][c0];
    float4 b1 = *(const float4*)&Bt[k+1][c0];
    float4 b2 = *(const float4*)&Bt[k+2][c0];
    float4 b3 = *(const float4*)&Bt[k+3][c0];
    float4 a0 = *(const float4*)&At[ra+0][koff+k];
    float4 a1 = *(const float4*)&At[ra+1][koff+k];
    float4 a2 = *(const float4*)&At[ra+2][koff+k];
    float4 a3 = *(const float4*)&At[ra+3][koff+k];
    micro4(a0, b0,b1,b2,b3, acc[0]);
    micro4(a1, b0,b1,b2,b3, acc[1]);
    micro4(a2, b0,b1,b2,b3, acc[2]);
    micro4(a3, b0,b1,b2,b3, acc[3]);
  }
}

// ---------------- kernels ----------------

// h = relu(x @ W_emb + b_emb) + pos_table[:n]; W_emb from global (runs once, small)
__global__ __launch_bounds__(256) void k_embed(const float* __restrict__ x, const float* __restrict__ W,
                                               const float* __restrict__ bias, const float* __restrict__ pos,
                                               float* __restrict__ h) {
  __shared__ float xs[32][FEAT];    // 8KB
  const int t = threadIdx.x;
  const int row0 = blockIdx.x * 32;
  {
    const float4* xv = (const float4*)(x + (size_t)row0 * FEAT);
    float4* xd = (float4*)&xs[0][0];
    for (int i = t; i < 32*FEAT/4; i += 256) xd[i] = xv[i];
  }
  __syncthreads();
  const int c0 = (t & 31) * 4;
  const int r0 = (t >> 5) * 4;
  float acc[4][4] = {};
  #pragma unroll 2
  for (int k = 0; k < FEAT; k += 4) {
    float4 b0 = *(const float4*)&W[(k+0)*HID + c0];
    float4 b1 = *(const float4*)&W[(k+1)*HID + c0];
    float4 b2 = *(const float4*)&W[(k+2)*HID + c0];
    float4 b3 = *(const float4*)&W[(k+3)*HID + c0];
    float4 a0 = *(const float4*)&xs[r0+0][k];
    float4 a1 = *(const float4*)&xs[r0+1][k];
    float4 a2 = *(const float4*)&xs[r0+2][k];
    float4 a3 = *(const float4*)&xs[r0+3][k];
    micro4(a0, b0,b1,b2,b3, acc[0]);
    micro4(a1, b0,b1,b2,b3, acc[1]);
    micro4(a2, b0,b1,b2,b3, acc[2]);
    micro4(a3, b0,b1,b2,b3, acc[3]);
  }
  const float4 bv = *(const float4*)&bias[c0];
  #pragma unroll
  for (int r = 0; r < 4; ++r) {
    const int row = row0 + r0 + r;
    const int n = row & (NSEQ - 1);
    const float4 pv = *(const float4*)&pos[(size_t)n*HID + c0];
    float4 o;
    o.x = fmaxf(acc[r][0] + bv.x, 0.f) + pv.x;
    o.y = fmaxf(acc[r][1] + bv.y, 0.f) + pv.y;
    o.z = fmaxf(acc[r][2] + bv.z, 0.f) + pv.z;
    o.w = fmaxf(acc[r][3] + bv.w, 0.f) + pv.w;
    *(float4*)&h[(size_t)row*HID + c0] = o;
  }
}

// s[b,n] = ((n - (N-1)/2)/N, 0, 0)
__global__ __launch_bounds__(256) void k_sinit(float* __restrict__ s) {
  const int i = blockIdx.x * 256 + threadIdx.x;
  if (i < RTOT) {
    const int n = i & (NSEQ - 1);
    s[(size_t)i*3 + 0] = ((float)n - (NSEQ - 1) * 0.5f) / (float)NSEQ;
    s[(size_t)i*3 + 1] = 0.f;
    s[(size_t)i*3 + 2] = 0.f;
  }
}

// out = relu(in @ W + b); W async-staged in 32-row slabs, double-buffered
__global__ __launch_bounds__(256) void k_msg(const float* __restrict__ in, const float* __restrict__ W,
                                             const float* __restrict__ bias, float* __restrict__ out) {
  __shared__ float as[32][HID];      // 16KB
  __shared__ float Bs[2][32][HID];   // 32KB -> 48KB total
  const int t = threadIdx.x;
  const int row0 = blockIdx.x * 32;
  {
    const float4* av = (const float4*)(in + (size_t)row0 * HID);
    float4* ad = (float4*)&as[0][0];
    for (int i = t; i < 32*HID/4; i += 256) ad[i] = av[i];
  }
  stage_slab(W, &Bs[0][0][0], t);
  __syncthreads();   // drains A ds_writes + slab0
  const int c0 = (t & 31) * 4;
  const int r0 = (t >> 5) * 4;
  float acc[4][4] = {};
  #pragma unroll 1
  for (int st = 0; st < 4; ++st) {
    if (st < 3) stage_slab(W + (size_t)(st+1)*32*HID, &Bs[(st+1)&1][0][0], t);
    gemm_slab<HID>(as, r0, st*32, Bs[st&1], c0, acc);
    __syncthreads();
  }
  const float4 bv = *(const float4*)&bias[c0];
  #pragma unroll
  for (int r = 0; r < 4; ++r) {
    float4 o;
    o.x = fmaxf(acc[r][0] + bv.x, 0.f);
    o.y = fmaxf(acc[r][1] + bv.y, 0.f);
    o.z = fmaxf(acc[r][2] + bv.z, 0.f);
    o.w = fmaxf(acc[r][3] + bv.w, 0.f);
    *(float4*)&out[(size_t)(row0 + r0 + r)*HID + c0] = o;
  }
}

// agg[b,i,:] = sum_j exp(-100*||s_i-s_j||^2)*mask[b,i,j]*m[b,j,:]
// j-tile=32: m slab async-staged (double-buffered), next mask tile prefetched
// to regs under the gemm, exp-tile written to the idle ws buffer. 1 barrier/tile.
__global__ __launch_bounds__(256) void k_agg(const float* __restrict__ s, const float* __restrict__ mask,
                                             const float* __restrict__ m, float* __restrict__ agg) {
  __shared__ float sj[NSEQ][3];      // 6KB
  __shared__ float ws[2][32][32];    // 8KB
  __shared__ float ms[2][32][HID];   // 32KB -> 46KB total
  const int t = threadIdx.x;
  const int b = blockIdx.x;
  const int i0 = blockIdx.y * 32;
  {
    const float* sp = s + (size_t)b * NSEQ * 3;
    for (int i = t; i < NSEQ*3; i += 256) (&sj[0][0])[i] = sp[i];
  }
  __syncthreads();
  const float* maskb = mask + (size_t)b * NSEQ * NSEQ;
  const float* mb = m + (size_t)b * NSEQ * HID;
  stage_slab(mb, &ms[0][0][0], t);
  #pragma unroll
  for (int p = 0; p < 4; ++p) {
    const int e = t + p*256, wi = e >> 5, wj = e & 31;
    const float dx = sj[i0+wi][0] - sj[wj][0];
    const float dy = sj[i0+wi][1] - sj[wj][1];
    const float dz = sj[i0+wi][2] - sj[wj][2];
    const float mk = maskb[(size_t)(i0+wi)*NSEQ + wj];
    ws[0][wi][wj] = __expf(-100.0f*(dx*dx + dy*dy + dz*dz)) * mk;
  }
  __syncthreads();
  const int c0 = (t & 31) * 4;
  const int r0 = (t >> 5) * 4;
  float acc[4][4] = {};
  #pragma unroll 1
  for (int jt = 0; jt < 16; ++jt) {
    const int cur = jt & 1, nxt = cur ^ 1;
    float mk[4];
    if (jt < 15) {
      stage_slab(mb + (size_t)(jt+1)*32*HID, &ms[nxt][0][0], t);
      const int j0n = (jt+1) * 32;
      #pragma unroll
      for (int p = 0; p < 4; ++p) {
        const int e = t + p*256, wi = e >> 5, wj = e & 31;
        mk[p] = maskb[(size_t)(i0+wi)*NSEQ + j0n + wj];
      }
    }
    gemm_slab<32>(ws[cur], r0, 0, ms[cur], c0, acc);
    if (jt < 15) {
      const int j0n = (jt+1) * 32;
      #pragma unroll
      for (int p = 0; p < 4; ++p) {
        const int e = t + p*256, wi = e >> 5, wj = e & 31;
        const float dx = sj[i0+wi][0] - sj[j0n+wj][0];
        const float dy = sj[i0+wi][1] - sj[j0n+wj][1];
        const float dz = sj[i0+wi][2] - sj[j0n+wj][2];
        ws[nxt][wi][wj] = __expf(-100.0f*(dx*dx + dy*dy + dz*dz)) * mk[p];
      }
    }
    __syncthreads();
  }
  #pragma unroll
  for (int r = 0; r < 4; ++r) {
    float4 o = make_float4(acc[r][0], acc[r][1], acc[r][2], acc[r][3]);
    *(float4*)&agg[((size_t)b*NSEQ + i0 + r0 + r)*HID + c0] = o;
  }
}

// k_zr: z = sigm(agg@Wz + h@Uz + bz); rh = sigm(agg@Wr + h@Ur + br) * h
// 16 async slab-steps (Wz,Uz,Wr,Ur x 4), double-buffered; acc chosen by uniform branch.
__global__ __launch_bounds__(256) void k_zr(const float* __restrict__ agg, const float* __restrict__ h,
    const float* __restrict__ Wz, const float* __restrict__ Uz, const float* __restrict__ bz,
    const float* __restrict__ Wr, const float* __restrict__ Ur, const float* __restrict__ br,
    float* __restrict__ zbuf, float* __restrict__ rhbuf) {
  __shared__ float ah[64][HID];      // rows 0-31 agg, 32-63 h (32KB)
  __shared__ float Bs[2][32][HID];   // 32KB -> 64KB total
  const int t = threadIdx.x;
  const int row0 = blockIdx.x * 32;
  const int c0 = (t & 31) * 4;
  const int r0 = (t >> 5) * 4;
  {
    const float4* av = (const float4*)(agg + (size_t)row0 * HID);
    const float4* hv = (const float4*)(h + (size_t)row0 * HID);
    float4* d = (float4*)&ah[0][0];
    for (int i = t; i < 32*HID/4; i += 256) { d[i] = av[i]; d[i + 32*HID/4] = hv[i]; }
  }
  stage_slab(Wz, &Bs[0][0][0], t);
  __syncthreads();
  float accz[4][4] = {};
  float accr[4][4] = {};
  #pragma unroll 1
  for (int st = 0; st < 16; ++st) {
    const int g1 = st + 1;
    if (g1 < 16) {
      const float* wn = (g1 < 4) ? Wz : (g1 < 8) ? Uz : (g1 < 12) ? Wr : Ur;
      stage_slab(wn + (size_t)(g1 & 3) * 32 * HID, &Bs[g1 & 1][0][0], t);
    }
    const int ra = ((st >> 2) & 1) ? (32 + r0) : r0;   // agg rows or h rows
    const int koff = (st & 3) * 32;
    if (st < 8) gemm_slab<HID>(ah, ra, koff, Bs[st & 1], c0, accz);
    else        gemm_slab<HID>(ah, ra, koff, Bs[st & 1], c0, accr);
    __syncthreads();
  }
  const float4 bzv = *(const float4*)&bz[c0];
  const float4 brv = *(const float4*)&br[c0];
  #pragma unroll
  for (int r = 0; r < 4; ++r) {
    const float4 hv4 = *(const float4*)&ah[32 + r0 + r][c0];
    float4 zo, ro;
    zo.x = sigm(accz[r][0] + bzv.x);
    zo.y = sigm(accz[r][1] + bzv.y);
    zo.z = sigm(accz[r][2] + bzv.z);
    zo.w = sigm(accz[r][3] + bzv.w);
    ro.x = sigm(accr[r][0] + brv.x) * hv4.x;
    ro.y = sigm(accr[r][1] + brv.y) * hv4.y;
    ro.z = sigm(accr[r][2] + brv.z) * hv4.z;
    ro.w = sigm(accr[r][3] + brv.w) * hv4.w;
    const size_t o = (size_t)(row0 + r0 + r) * HID + c0;
    *(float4*)&zbuf[o]  = zo;
    *(float4*)&rhbuf[o] = ro;
  }
}

// k_cand: h <- (1-z)*h + z*tanh(agg@Wh + rh@Uh + bh); 8 async slab-steps.
__global__ __launch_bounds__(256) void k_cand(const float* __restrict__ agg, const float* __restrict__ rh,
    const float* __restrict__ Wh, const float* __restrict__ Uh, const float* __restrict__ bh,
    const float* __restrict__ zbuf, float* __restrict__ h) {
  __shared__ float ah[64][HID];      // rows 0-31 agg, 32-63 rh
  __shared__ float Bs[2][32][HID];
  const int t = threadIdx.x;
  const int row0 = blockIdx.x * 32;
  const int c0 = (t & 31) * 4;
  const int r0 = (t >> 5) * 4;
  {
    const float4* av = (const float4*)(agg + (size_t)row0 * HID);
    const float4* rv = (const float4*)(rh + (size_t)row0 * HID);
    float4* d = (float4*)&ah[0][0];
    for (int i = t; i < 32*HID/4; i += 256) { d[i] = av[i]; d[i + 32*HID/4] = rv[i]; }
  }
  stage_slab(Wh, &Bs[0][0][0], t);
  __syncthreads();
  float acc[4][4] = {};
  #pragma unroll 1
  for (int st = 0; st < 8; ++st) {
    const int g1 = st + 1;
    if (g1 < 8) {
      const float* wn = (g1 < 4) ? Wh : Uh;
      stage_slab(wn + (size_t)(g1 & 3) * 32 * HID, &Bs[g1 & 1][0][0], t);
    }
    const int ra = (st >= 4) ? (32 + r0) : r0;
    const int koff = (st & 3) * 32;
    gemm_slab<HID>(ah, ra, koff, Bs[st & 1], c0, acc);
    __syncthreads();
  }
  const float4 bhv = *(const float4*)&bh[c0];
  #pragma unroll
  for (int r = 0; r < 4; ++r) {
    const size_t o = (size_t)(row0 + r0 + r) * HID + c0;
    const float4 zv = *(const float4*)&zbuf[o];
    const float4 hv = *(const float4*)&h[o];
    float4 res;
    res.x = (1.f - zv.x) * hv.x + zv.x * tanh_fast(acc[r][0] + bhv.x);
    res.y = (1.f - zv.y) * hv.y + zv.y * tanh_fast(acc[r][1] + bhv.y);
    res.z = (1.f - zv.z) * hv.z + zv.z * tanh_fast(acc[r][2] + bhv.z);
    res.w = (1.f - zv.w) * hv.w + zv.w * tanh_fast(acc[r][3] + bhv.w);
    *(float4*)&h[o] = res;
  }
}

// positional GRU: s <- (1-zs)s + zs*tanh(h@Wph + (rs*s)@Uph + bph); one wave per row
__global__ __launch_bounds__(256) void k_posgru(const float* __restrict__ h, float* __restrict__ s,
    const float* __restrict__ Wpz, const float* __restrict__ Upz, const float* __restrict__ bpz,
    const float* __restrict__ Wpr, const float* __restrict__ Upr, const float* __restrict__ bpr,
    const float* __restrict__ Wph, const float* __restrict__ Uph, const float* __restrict__ bph) {
  const int lane = threadIdx.x & 63;
  const int w = threadIdx.x >> 6;
  const int row = blockIdx.x * 4 + w;
  const int k0 = lane * 2;
  const float2 hv = *(const float2*)&h[(size_t)row*HID + k0];
  float p[9];
  #pragma unroll
  for (int c = 0; c < 3; ++c) {
    p[c]     = hv.x * Wpz[k0*3 + c] + hv.y * Wpz[(k0+1)*3 + c];
    p[3 + c] = hv.x * Wpr[k0*3 + c] + hv.y * Wpr[(k0+1)*3 + c];
    p[6 + c] = hv.x * Wph[k0*3 + c] + hv.y * Wph[(k0+1)*3 + c];
  }
  #pragma unroll
  for (int off = 32; off > 0; off >>= 1) {
    #pragma unroll
    for (int q = 0; q < 9; ++q) p[q] += __shfl_xor(p[q], off, 64);
  }
  const float s0 = s[(size_t)row*3 + 0], s1 = s[(size_t)row*3 + 1], s2 = s[(size_t)row*3 + 2];
  float zs[3], rs[3], ss[3];
  #pragma unroll
  for (int c = 0; c < 3; ++c) {
    zs[c] = sigm(p[c]     + s0*Upz[c] + s1*Upz[3+c] + s2*Upz[6+c] + bpz[c]);
    rs[c] = sigm(p[3 + c] + s0*Upr[c] + s1*Upr[3+c] + s2*Upr[6+c] + bpr[c]);
  }
  const float t0 = rs[0]*s0, t1 = rs[1]*s1, t2 = rs[2]*s2;
  #pragma unroll
  for (int c = 0; c < 3; ++c)
    ss[c] = tanh_fast(p[6 + c] + t0*Uph[c] + t1*Uph[3+c] + t2*Uph[6+c] + bph[c]);
  if (lane == 0) {
    s[(size_t)row*3 + 0] = (1.f - zs[0])*s0 + zs[0]*ss[0];
    s[(size_t)row*3 + 1] = (1.f - zs[1])*s1 + zs[1]*ss[1];
    s[(size_t)row*3 + 2] = (1.f - zs[2])*s2 + zs[2]*ss[2];
  }
}

// A[b,i,j] = exp(-100*||s_i-s_j||^2)*mask   (16 i-rows per block)
__global__ __launch_bounds__(256) void k_finalA(const float* __restrict__ s, const float* __restrict__ mask,
                                                float* __restrict__ A) {
  __shared__ float sj[NSEQ][3];
  const int t = threadIdx.x;
  const int b = blockIdx.x;
  const int i0 = blockIdx.y * 16;
  {
    const float* sp = s + (size_t)b * NSEQ * 3;
    for (int i = t; i < NSEQ*3; i += 256) (&sj[0][0])[i] = sp[i];
  }
  __syncthreads();
  #pragma unroll
  for (int p = 0; p < 8; ++p) {
    const int e = t + p*256;          // 0..2047
    const int ii = e >> 7;            // 0..15
    const int j4 = (e & 127) * 4;     // 0..508
    const float six = sj[i0+ii][0], siy = sj[i0+ii][1], siz = sj[i0+ii][2];
    const size_t base = ((size_t)b*NSEQ + i0 + ii)*NSEQ + j4;
    const float4 mk = *(const float4*)&mask[base];
    float4 o;
    {
      float dx = six - sj[j4+0][0], dy = siy - sj[j4+0][1], dz = siz - sj[j4+0][2];
      o.x = __expf(-100.0f*(dx*dx + dy*dy + dz*dz)) * mk.x;
    }
    {
      float dx = six - sj[j4+1][0], dy = siy - sj[j4+1][1], dz = siz - sj[j4+1][2];
      o.y = __expf(-100.0f*(dx*dx + dy*dy + dz*dz)) * mk.y;
    }
    {
      float dx = six - sj[j4+2][0], dy = siy - sj[j4+2][1], dz = siz - sj[j4+2][2];
      o.z = __expf(-100.0f*(dx*dx + dy*dy + dz*dz)) * mk.z;
    }
    {
      float dx = six - sj[j4+3][0], dy = siy - sj[j4+3][1], dz = siz - sj[j4+3][2];
      o.w = __expf(-100.0f*(dx*dx + dy*dy + dz*dz)) * mk.w;
    }
    *(float4*)&A[base] = o;
  }
}

// ---------------- launcher ----------------

extern "C" void kernel_launch(void* const* d_in, const int* in_sizes, int n_in,
                              void* d_out, int out_size, void* d_ws, size_t ws_size,
                              hipStream_t stream) {
  const float* x      = (const float*)d_in[0];
  const float* mask   = (const float*)d_in[1];
  const float* W_emb  = (const float*)d_in[2];
  const float* b_emb  = (const float*)d_in[3];
  const float* pos    = (const float*)d_in[4];
  const float* Wm     = (const float*)d_in[5];
  const float* bm     = (const float*)d_in[6];
  const float* Wz     = (const float*)d_in[7];
  const float* Uz     = (const float*)d_in[8];
  const float* bz     = (const float*)d_in[9];
  const float* Wr     = (const float*)d_in[10];
  const float* Ur     = (const float*)d_in[11];
  const float* br     = (const float*)d_in[12];
  const float* Wh     = (const float*)d_in[13];
  const float* Uh     = (const float*)d_in[14];
  const float* bh     = (const float*)d_in[15];
  const float* Wpz    = (const float*)d_in[16];
  const float* Upz    = (const float*)d_in[17];
  const float* bpz    = (const float*)d_in[18];
  const float* Wpr    = (const float*)d_in[19];
  const float* Upr    = (const float*)d_in[20];
  const float* bpr    = (const float*)d_in[21];
  const float* Wph    = (const float*)d_in[22];
  const float* Uph    = (const float*)d_in[23];
  const float* bph    = (const float*)d_in[24];

  float* out = (float*)d_out;
  float* h   = (float*)d_ws;                       // 16 MB
  float* s   = h + (size_t)RTOT * HID;             // 0.4 MB
  // d_out is exactly 4 * RTOT*HID floats; all four scratch views are dead
  // before k_finalA overwrites the full output.
  float* m   = out;                                // [0, 4M)
  float* agg = out + (size_t)RTOT * HID;           // [4M, 8M)
  float* zb  = out + (size_t)2 * RTOT * HID;       // [8M, 12M)
  float* rhb = out + (size_t)3 * RTOT * HID;       // [12M, 16M)

  k_embed<<<RTOT/32, 256, 0, stream>>>(x, W_emb, b_emb, pos, h);
  k_sinit<<<RTOT/256, 256, 0, stream>>>(s);

  for (int i = 0; i < NITER; ++i) {
    const size_t wo = (size_t)i * HID * HID;
    const size_t bo = (size_t)i * HID;
    k_msg<<<RTOT/32, 256, 0, stream>>>(h, Wm + wo, bm + bo, m);
    k_agg<<<dim3(BSZ, NSEQ/32), 256, 0, stream>>>(s, mask, m, agg);
    k_zr<<<RTOT/32, 256, 0, stream>>>(agg, h,
        Wz + wo, Uz + wo, bz + bo,
        Wr + wo, Ur + wo, br + bo, zb, rhb);
    k_cand<<<RTOT/32, 256, 0, stream>>>(agg, rhb,
        Wh + wo, Uh + wo, bh + bo, zb, h);
    k_posgru<<<RTOT/4, 256, 0, stream>>>(h, s, Wpz, Upz, bpz, Wpr, Upr, bpr, Wph, Uph, bph);
  }
  k_finalA<<<dim3(BSZ, NSEQ/16), 256, 0, stream>>>(s, mask, out);
}

// Round 6
// 801.700 us; speedup vs baseline: 7.7832x; 1.0754x over previous
//
#include <hip/hip_runtime.h>
#include <math.h>

#define BSZ  64
#define NSEQ 512
#define FEAT 64
#define HID  128
#define NITER 3
#define RTOT (BSZ*NSEQ)   // 32768 rows
#define LDAP 136          // padded LDS plane stride (shorts): 272B = 17*16 -> aligned + ~2-way banks

typedef __attribute__((ext_vector_type(8))) short bf16x8;
typedef __attribute__((ext_vector_type(4))) float f32x4;
typedef unsigned int u32;

// ---------------- helpers ----------------

__device__ __forceinline__ float sigm(float v) {
  v = fminf(fmaxf(v, -30.f), 30.f);
  return 1.0f / (1.0f + __expf(-v));
}
__device__ __forceinline__ float tanh_fast(float v) {
  v = fminf(fmaxf(v, -15.f), 15.f);
  float e = __expf(2.0f * v);
  return (e - 1.0f) / (e + 1.0f);
}

// split fp32 into (hi,lo) bf16 pair packed in one u32: a ~= f(hi) + f(lo), err ~2^-17|a|
__device__ __forceinline__ u32 pack_split(float a) {
  u32 ub = __float_as_uint(a);
  u32 hi = ub >> 16;                       // truncated bf16
  float res = a - __uint_as_float(hi << 16);
  u32 lo = __float_as_uint(res) >> 16;
  return (hi << 16) | lo;
}
__device__ __forceinline__ float bf2f(short v) {
  return __uint_as_float(((u32)(unsigned short)v) << 16);
}

// 3-term split-bf16 product: ah*bh + ah*bl + al*bh  (error ~2^-18)
__device__ __forceinline__ f32x4 mfma3(bf16x8 ah, bf16x8 al, bf16x8 bh, bf16x8 bl, f32x4 c) {
  c = __builtin_amdgcn_mfma_f32_16x16x32_bf16(ah, bh, c, 0, 0, 0);
  c = __builtin_amdgcn_mfma_f32_16x16x32_bf16(ah, bl, c, 0, 0, 0);
  c = __builtin_amdgcn_mfma_f32_16x16x32_bf16(al, bh, c, 0, 0, 0);
  return c;
}

// stage packed-u32 [64][128] global tile -> two LDS short planes [64][LDAP]
// 512 threads: each handles 16 consecutive u32 (row = t>>3, col = (t&7)*16)
__device__ __forceinline__ void stage_planes(const u32* __restrict__ g, short* hiP, short* loP, int t) {
  const int row = t >> 3, col = (t & 7) * 16;
  const u32* src = g + (size_t)row * HID + col;
  #pragma unroll
  for (int i = 0; i < 4; ++i) {
    uint4 u = *(const uint4*)(src + i * 4);
    *(short4*)&hiP[row * LDAP + col + i * 4] =
        make_short4((short)(u.x >> 16), (short)(u.y >> 16), (short)(u.z >> 16), (short)(u.w >> 16));
    *(short4*)&loP[row * LDAP + col + i * 4] =
        make_short4((short)(u.x & 0xffff), (short)(u.y & 0xffff), (short)(u.z & 0xffff), (short)(u.w & 0xffff));
  }
}

// one full 128-K gate: A from LDS planes P[AP],P[AP+1], B from global weight planes.
// lane vars lrow,kgrp,ncol,nh must be in scope; acc[4] covers 4 n-tiles (64 cols).
#define GATE(ACC, AP, WHp, WLp) do { \
  _Pragma("unroll") \
  for (int ks_ = 0; ks_ < 4; ++ks_) { \
    bf16x8 ah_ = *(bf16x8*)&P[AP][lrow][ks_*32 + kgrp]; \
    bf16x8 al_ = *(bf16x8*)&P[(AP)+1][lrow][ks_*32 + kgrp]; \
    _Pragma("unroll") \
    for (int nt_ = 0; nt_ < 4; ++nt_) { \
      const int nn_ = nh*64 + nt_*16 + ncol; \
      bf16x8 bh_ = *(const bf16x8*)&(WHp)[(size_t)nn_*HID + ks_*32 + kgrp]; \
      bf16x8 bl_ = *(const bf16x8*)&(WLp)[(size_t)nn_*HID + ks_*32 + kgrp]; \
      ACC[nt_] = mfma3(ah_, al_, bh_, bl_, ACC[nt_]); \
    } \
  } \
} while (0)

__device__ __forceinline__ void micro4(const float4 a, const float4 b0, const float4 b1,
                                       const float4 b2, const float4 b3, float acc[4]) {
  acc[0] = fmaf(a.x, b0.x, acc[0]); acc[0] = fmaf(a.y, b1.x, acc[0]);
  acc[0] = fmaf(a.z, b2.x, acc[0]); acc[0] = fmaf(a.w, b3.x, acc[0]);
  acc[1] = fmaf(a.x, b0.y, acc[1]); acc[1] = fmaf(a.y, b1.y, acc[1]);
  acc[1] = fmaf(a.z, b2.y, acc[1]); acc[1] = fmaf(a.w, b3.y, acc[1]);
  acc[2] = fmaf(a.x, b0.z, acc[2]); acc[2] = fmaf(a.y, b1.z, acc[2]);
  acc[2] = fmaf(a.z, b2.z, acc[2]); acc[2] = fmaf(a.w, b3.z, acc[2]);
  acc[3] = fmaf(a.x, b0.w, acc[3]); acc[3] = fmaf(a.y, b1.w, acc[3]);
  acc[3] = fmaf(a.z, b2.w, acc[3]); acc[3] = fmaf(a.w, b3.w, acc[3]);
}

// ---------------- kernels ----------------

// one-time: split+transpose the 21 [128][128] weight mats -> bf16 hi/lo planes Wt[n][k]
// mat m = gate*3 + iter, gates: 0=Wm 1=Wz 2=Uz 3=Wr 4=Ur 5=Wh 6=Uh
__global__ __launch_bounds__(256) void k_prep(
    const float* __restrict__ Wm, const float* __restrict__ Wz, const float* __restrict__ Uz,
    const float* __restrict__ Wr, const float* __restrict__ Ur, const float* __restrict__ Wh,
    const float* __restrict__ Uh, short* __restrict__ wpl) {
  __shared__ float Wl[HID * HID];   // 64KB
  const int t = threadIdx.x;
  const int m = blockIdx.x;        // 0..20
  const int g = m / 3, it = m - g * 3;
  const float* src;
  switch (g) { case 0: src = Wm; break; case 1: src = Wz; break; case 2: src = Uz; break;
               case 3: src = Wr; break; case 4: src = Ur; break; case 5: src = Wh; break;
               default: src = Uh; }
  src += (size_t)it * HID * HID;
  for (int i = t; i < HID * HID / 4; i += 256) ((float4*)Wl)[i] = ((const float4*)src)[i];
  __syncthreads();
  short* dh = wpl + (size_t)m * 32768;
  short* dl = dh + 16384;
  const int n = t >> 1, kh = (t & 1) * 64;
  for (int k = 0; k < 64; k += 2) {
    u32 p0 = pack_split(Wl[(size_t)(kh + k) * HID + n]);
    u32 p1 = pack_split(Wl[(size_t)(kh + k + 1) * HID + n]);
    *(u32*)&dh[(size_t)n * HID + kh + k] = (p0 >> 16) | ((p1 >> 16) << 16);
    *(u32*)&dl[(size_t)n * HID + kh + k] = (p0 & 0xffffu) | ((p1 & 0xffffu) << 16);
  }
}

// h = relu(x @ W_emb + b_emb) + pos_table[:n] -> packed u32 planes (fp32 compute, small)
__global__ __launch_bounds__(256) void k_embed(const float* __restrict__ x, const float* __restrict__ W,
                                               const float* __restrict__ bias, const float* __restrict__ pos,
                                               u32* __restrict__ hP) {
  __shared__ float xs[32][FEAT];
  const int t = threadIdx.x;
  const int row0 = blockIdx.x * 32;
  {
    const float4* xv = (const float4*)(x + (size_t)row0 * FEAT);
    float4* xd = (float4*)&xs[0][0];
    for (int i = t; i < 32 * FEAT / 4; i += 256) xd[i] = xv[i];
  }
  __syncthreads();
  const int c0 = (t & 31) * 4;
  const int r0 = (t >> 5) * 4;
  float acc[4][4] = {};
  #pragma unroll 2
  for (int k = 0; k < FEAT; k += 4) {
    float4 b0 = *(const float4*)&W[(k + 0) * HID + c0];
    float4 b1 = *(const float4*)&W[(k + 1) * HID + c0];
    float4 b2 = *(const float4*)&W[(k + 2) * HID + c0];
    float4 b3 = *(const float4*)&W[(k + 3) * HID + c0];
    float4 a0 = *(const float4*)&xs[r0 + 0][k];
    float4 a1 = *(const float4*)&xs[r0 + 1][k];
    float4 a2 = *(const float4*)&xs[r0 + 2][k];
    float4 a3 = *(const float4*)&xs[r0 + 3][k];
    micro4(a0, b0, b1, b2, b3, acc[0]);
    micro4(a1, b0, b1, b2, b3, acc[1]);
    micro4(a2, b0, b1, b2, b3, acc[2]);
    micro4(a3, b0, b1, b2, b3, acc[3]);
  }
  const float4 bv = *(const float4*)&bias[c0];
  #pragma unroll
  for (int r = 0; r < 4; ++r) {
    const int row = row0 + r0 + r;
    const int n = row & (NSEQ - 1);
    const float4 pv = *(const float4*)&pos[(size_t)n * HID + c0];
    uint4 pk;
    pk.x = pack_split(fmaxf(acc[r][0] + bv.x, 0.f) + pv.x);
    pk.y = pack_split(fmaxf(acc[r][1] + bv.y, 0.f) + pv.y);
    pk.z = pack_split(fmaxf(acc[r][2] + bv.z, 0.f) + pv.z);
    pk.w = pack_split(fmaxf(acc[r][3] + bv.w, 0.f) + pv.w);
    *(uint4*)&hP[(size_t)row * HID + c0] = pk;
  }
}

__global__ __launch_bounds__(256) void k_sinit(float* __restrict__ s) {
  const int i = blockIdx.x * 256 + threadIdx.x;
  if (i < RTOT) {
    const int n = i & (NSEQ - 1);
    s[(size_t)i * 3 + 0] = ((float)n - (NSEQ - 1) * 0.5f) / (float)NSEQ;
    s[(size_t)i * 3 + 1] = 0.f;
    s[(size_t)i * 3 + 2] = 0.f;
  }
}

// m = relu(h @ Wm + bm) -> transposed bf16 planes mt[b][n][j] (hi/lo), 64 rows/block, 512 thr
__global__ __launch_bounds__(512) void k_msg(const u32* __restrict__ hP, const short* __restrict__ wpl,
                                             int iter, const float* __restrict__ bm,
                                             short* __restrict__ mtH, short* __restrict__ mtL) {
  __shared__ short P[2][64][LDAP];   // h hi/lo planes
  __shared__ short T[2][128][72];    // transpose buffer [n][j] hi/lo
  const int t = threadIdx.x;
  const int row0 = blockIdx.x * 64;
  stage_planes(hP + (size_t)row0 * HID, &P[0][0][0], &P[1][0][0], t);
  __syncthreads();
  const int l = t & 63, w = t >> 6;
  const int mt = w & 3, nh = w >> 2;
  const int lrow = mt * 16 + (l & 15);
  const int kgrp = (l >> 4) * 8;
  const int ncol = l & 15;
  f32x4 z4 = {0.f, 0.f, 0.f, 0.f};
  f32x4 acc[4];
  #pragma unroll
  for (int i = 0; i < 4; ++i) acc[i] = z4;
  {
    const short* WH = wpl + (size_t)(0 * 3 + iter) * 32768;
    const short* WL = WH + 16384;
    GATE(acc, 0, WH, WL);
  }
  const int rbase = mt * 16 + (l >> 4) * 4;
  #pragma unroll
  for (int nt = 0; nt < 4; ++nt) {
    const int cc = nh * 64 + nt * 16 + ncol;
    const float bmc = bm[cc];
    #pragma unroll
    for (int q = 0; q < 4; ++q) {
      u32 pk = pack_split(fmaxf(acc[nt][q] + bmc, 0.f));
      T[0][cc][rbase + q] = (short)(pk >> 16);
      T[1][cc][rbase + q] = (short)(pk & 0xffff);
    }
  }
  __syncthreads();
  const int b = row0 >> 9, j0 = row0 & (NSEQ - 1);
  const int n = t >> 2, jq = (t & 3) * 16;
  const size_t gbase = ((size_t)b * HID + n) * NSEQ + j0 + jq;
  *(bf16x8*)&mtH[gbase]     = *(bf16x8*)&T[0][n][jq];
  *(bf16x8*)&mtH[gbase + 8] = *(bf16x8*)&T[0][n][jq + 8];
  *(bf16x8*)&mtL[gbase]     = *(bf16x8*)&T[1][n][jq];
  *(bf16x8*)&mtL[gbase + 8] = *(bf16x8*)&T[1][n][jq + 8];
}

// agg = (exp(-100 d2)*mask) @ m : exp-tile built per 32-j slab in LDS (split bf16, dbuf),
// B-frags from transposed m-planes in global. Output packed u32.
__global__ __launch_bounds__(256) void k_agg(const float* __restrict__ s, const float* __restrict__ mask,
                                             const short* __restrict__ mtH, const short* __restrict__ mtL,
                                             u32* __restrict__ aggP) {
  __shared__ float sj[NSEQ][3];
  __shared__ short WH2[2][32][40];
  __shared__ short WL2[2][32][40];
  const int t = threadIdx.x;
  const int b = blockIdx.x;
  const int i0 = blockIdx.y * 32;
  {
    const float* sp = s + (size_t)b * NSEQ * 3;
    for (int i = t; i < NSEQ * 3; i += 256) (&sj[0][0])[i] = sp[i];
  }
  __syncthreads();
  const float* maskb = mask + (size_t)b * NSEQ * NSEQ;
  const int wi = t >> 3, wj4 = (t & 7) * 4;
  const float six = sj[i0 + wi][0], siy = sj[i0 + wi][1], siz = sj[i0 + wi][2];
  {  // slab 0 -> buf 0
    float4 mk = *(const float4*)&maskb[(size_t)(i0 + wi) * NSEQ + wj4];
    float vals[4] = {mk.x, mk.y, mk.z, mk.w};
    short ha[4], la[4];
    #pragma unroll
    for (int c = 0; c < 4; ++c) {
      const int jj = wj4 + c;
      float dx = six - sj[jj][0], dy = siy - sj[jj][1], dz = siz - sj[jj][2];
      u32 pk = pack_split(__expf(-100.0f * (dx * dx + dy * dy + dz * dz)) * vals[c]);
      ha[c] = (short)(pk >> 16); la[c] = (short)(pk & 0xffff);
    }
    *(short4*)&WH2[0][wi][wj4] = make_short4(ha[0], ha[1], ha[2], ha[3]);
    *(short4*)&WL2[0][wi][wj4] = make_short4(la[0], la[1], la[2], la[3]);
  }
  __syncthreads();
  const int l = t & 63, w = t >> 6;
  const int mt = w & 1, nh = w >> 1;
  const int kgrp = (l >> 4) * 8, ncol = l & 15;
  const int arow = mt * 16 + (l & 15);
  f32x4 z4 = {0.f, 0.f, 0.f, 0.f};
  f32x4 acc[4];
  #pragma unroll
  for (int i = 0; i < 4; ++i) acc[i] = z4;
  const size_t mtbase = (size_t)b * HID * NSEQ;
  #pragma unroll 1
  for (int jt = 0; jt < 16; ++jt) {
    const int buf = jt & 1;
    const int jn = (jt + 1) * 32;
    float4 mkn;
    if (jt < 15) mkn = *(const float4*)&maskb[(size_t)(i0 + wi) * NSEQ + jn + wj4];
    bf16x8 ah = *(bf16x8*)&WH2[buf][arow][kgrp];
    bf16x8 al = *(bf16x8*)&WL2[buf][arow][kgrp];
    #pragma unroll
    for (int nt = 0; nt < 4; ++nt) {
      const int nn = nh * 64 + nt * 16 + ncol;
      const size_t off = mtbase + (size_t)nn * NSEQ + jt * 32 + kgrp;
      acc[nt] = mfma3(ah, al, *(const bf16x8*)&mtH[off], *(const bf16x8*)&mtL[off], acc[nt]);
    }
    if (jt < 15) {
      float vals[4] = {mkn.x, mkn.y, mkn.z, mkn.w};
      short ha[4], la[4];
      #pragma unroll
      for (int c = 0; c < 4; ++c) {
        const int jj = jn + wj4 + c;
        float dx = six - sj[jj][0], dy = siy - sj[jj][1], dz = siz - sj[jj][2];
        u32 pk = pack_split(__expf(-100.0f * (dx * dx + dy * dy + dz * dz)) * vals[c]);
        ha[c] = (short)(pk >> 16); la[c] = (short)(pk & 0xffff);
      }
      *(short4*)&WH2[buf ^ 1][wi][wj4] = make_short4(ha[0], ha[1], ha[2], ha[3]);
      *(short4*)&WL2[buf ^ 1][wi][wj4] = make_short4(la[0], la[1], la[2], la[3]);
    }
    __syncthreads();
  }
  #pragma unroll
  for (int nt = 0; nt < 4; ++nt) {
    const int cc = nh * 64 + nt * 16 + ncol;
    #pragma unroll
    for (int q = 0; q < 4; ++q) {
      const int grow = i0 + mt * 16 + (l >> 4) * 4 + q;
      aggP[((size_t)b * NSEQ + grow) * HID + cc] = pack_split(acc[nt][q]);
    }
  }
}

// fused GRU: 6 gates (Wz,Uz,Wr,Ur,Wh,Uh), rh computed mid-kernel into the h LDS planes.
// 64 rows/block, 512 threads, 3 barriers total. h packed u32 updated in place.
__global__ __launch_bounds__(512) void k_zrc(
    const u32* __restrict__ aggP, u32* __restrict__ hP,
    const short* __restrict__ wpl, int iter,
    const float* __restrict__ bz, const float* __restrict__ br, const float* __restrict__ bhh) {
  __shared__ short P[4][64][LDAP];   // 0,1: agg hi/lo; 2,3: h hi/lo (later rh hi/lo)
  const int t = threadIdx.x;
  const int row0 = blockIdx.x * 64;
  stage_planes(aggP + (size_t)row0 * HID, &P[0][0][0], &P[1][0][0], t);
  stage_planes(hP + (size_t)row0 * HID, &P[2][0][0], &P[3][0][0], t);
  __syncthreads();
  const int l = t & 63, w = t >> 6;
  const int mt = w & 3, nh = w >> 2;
  const int lrow = mt * 16 + (l & 15);
  const int kgrp = (l >> 4) * 8;
  const int ncol = l & 15;
  f32x4 z4 = {0.f, 0.f, 0.f, 0.f};
  f32x4 accz[4], accr[4];
  #pragma unroll
  for (int i = 0; i < 4; ++i) { accz[i] = z4; accr[i] = z4; }
  #pragma unroll 1
  for (int g = 0; g < 4; ++g) {   // Wz(agg), Uz(h), Wr(agg), Ur(h)
    const short* WH = wpl + (size_t)((g + 1) * 3 + iter) * 32768;
    const short* WL = WH + 16384;
    const int ap = (g & 1) * 2;
    if (g < 2) { GATE(accz, ap, WH, WL); }
    else       { GATE(accr, ap, WH, WL); }
  }
  const int rbase = mt * 16 + (l >> 4) * 4;
  float hreg[4][4];
  float rhv[4][4];
  #pragma unroll
  for (int nt = 0; nt < 4; ++nt) {
    const int cc = nh * 64 + nt * 16 + ncol;
    const float brc = br[cc];
    #pragma unroll
    for (int q = 0; q < 4; ++q) {
      float hv = bf2f(P[2][rbase + q][cc]) + bf2f(P[3][rbase + q][cc]);
      hreg[nt][q] = hv;
      rhv[nt][q] = sigm(accr[nt][q] + brc) * hv;
    }
  }
  __syncthreads();   // all gates done reading h planes
  #pragma unroll
  for (int nt = 0; nt < 4; ++nt) {
    const int cc = nh * 64 + nt * 16 + ncol;
    #pragma unroll
    for (int q = 0; q < 4; ++q) {
      u32 pk = pack_split(rhv[nt][q]);
      P[2][rbase + q][cc] = (short)(pk >> 16);
      P[3][rbase + q][cc] = (short)(pk & 0xffff);
    }
  }
  __syncthreads();   // rh planes ready
  #pragma unroll
  for (int i = 0; i < 4; ++i) accr[i] = z4;   // reuse as cand accumulator
  {
    const short* WH = wpl + (size_t)(5 * 3 + iter) * 32768;   // Wh (A=agg)
    const short* WL = WH + 16384;
    GATE(accr, 0, WH, WL);
  }
  {
    const short* WH = wpl + (size_t)(6 * 3 + iter) * 32768;   // Uh (A=rh)
    const short* WL = WH + 16384;
    GATE(accr, 2, WH, WL);
  }
  #pragma unroll
  for (int nt = 0; nt < 4; ++nt) {
    const int cc = nh * 64 + nt * 16 + ncol;
    const float bzc = bz[cc], bhc = bhh[cc];
    #pragma unroll
    for (int q = 0; q < 4; ++q) {
      float z = sigm(accz[nt][q] + bzc);
      float cand = tanh_fast(accr[nt][q] + bhc);
      float hn = (1.f - z) * hreg[nt][q] + z * cand;
      hP[(size_t)(row0 + rbase + q) * HID + cc] = pack_split(hn);
    }
  }
}

// positional GRU on packed h
__global__ __launch_bounds__(256) void k_posgru(const u32* __restrict__ hP, float* __restrict__ s,
    const float* __restrict__ Wpz, const float* __restrict__ Upz, const float* __restrict__ bpz,
    const float* __restrict__ Wpr, const float* __restrict__ Upr, const float* __restrict__ bpr,
    const float* __restrict__ Wph, const float* __restrict__ Uph, const float* __restrict__ bph) {
  const int lane = threadIdx.x & 63;
  const int w = threadIdx.x >> 6;
  const int row = blockIdx.x * 4 + w;
  const int k0 = lane * 2;
  const uint2 hv2 = *(const uint2*)&hP[(size_t)row * HID + k0];
  const float hx = bf2f((short)(hv2.x >> 16)) + bf2f((short)(hv2.x & 0xffff));
  const float hy = bf2f((short)(hv2.y >> 16)) + bf2f((short)(hv2.y & 0xffff));
  float p[9];
  #pragma unroll
  for (int c = 0; c < 3; ++c) {
    p[c]     = hx * Wpz[k0 * 3 + c] + hy * Wpz[(k0 + 1) * 3 + c];
    p[3 + c] = hx * Wpr[k0 * 3 + c] + hy * Wpr[(k0 + 1) * 3 + c];
    p[6 + c] = hx * Wph[k0 * 3 + c] + hy * Wph[(k0 + 1) * 3 + c];
  }
  #pragma unroll
  for (int off = 32; off > 0; off >>= 1) {
    #pragma unroll
    for (int q = 0; q < 9; ++q) p[q] += __shfl_xor(p[q], off, 64);
  }
  const float s0 = s[(size_t)row * 3 + 0], s1 = s[(size_t)row * 3 + 1], s2 = s[(size_t)row * 3 + 2];
  float zs[3], rs[3], ss[3];
  #pragma unroll
  for (int c = 0; c < 3; ++c) {
    zs[c] = sigm(p[c]     + s0 * Upz[c] + s1 * Upz[3 + c] + s2 * Upz[6 + c] + bpz[c]);
    rs[c] = sigm(p[3 + c] + s0 * Upr[c] + s1 * Upr[3 + c] + s2 * Upr[6 + c] + bpr[c]);
  }
  const float t0 = rs[0] * s0, t1 = rs[1] * s1, t2 = rs[2] * s2;
  #pragma unroll
  for (int c = 0; c < 3; ++c)
    ss[c] = tanh_fast(p[6 + c] + t0 * Uph[c] + t1 * Uph[3 + c] + t2 * Uph[6 + c] + bph[c]);
  if (lane == 0) {
    s[(size_t)row * 3 + 0] = (1.f - zs[0]) * s0 + zs[0] * ss[0];
    s[(size_t)row * 3 + 1] = (1.f - zs[1]) * s1 + zs[1] * ss[1];
    s[(size_t)row * 3 + 2] = (1.f - zs[2]) * s2 + zs[2] * ss[2];
  }
}

// A[b,i,j] = exp(-100*||s_i-s_j||^2)*mask
__global__ __launch_bounds__(256) void k_finalA(const float* __restrict__ s, const float* __restrict__ mask,
                                                float* __restrict__ A) {
  __shared__ float sj[NSEQ][3];
  const int t = threadIdx.x;
  const int b = blockIdx.x;
  const int i0 = blockIdx.y * 16;
  {
    const float* sp = s + (size_t)b * NSEQ * 3;
    for (int i = t; i < NSEQ * 3; i += 256) (&sj[0][0])[i] = sp[i];
  }
  __syncthreads();
  #pragma unroll
  for (int p = 0; p < 8; ++p) {
    const int e = t + p * 256;
    const int ii = e >> 7;
    const int j4 = (e & 127) * 4;
    const float six = sj[i0 + ii][0], siy = sj[i0 + ii][1], siz = sj[i0 + ii][2];
    const size_t base = ((size_t)b * NSEQ + i0 + ii) * NSEQ + j4;
    const float4 mk = *(const float4*)&mask[base];
    float4 o;
    { float dx = six - sj[j4+0][0], dy = siy - sj[j4+0][1], dz = siz - sj[j4+0][2];
      o.x = __expf(-100.0f*(dx*dx + dy*dy + dz*dz)) * mk.x; }
    { float dx = six - sj[j4+1][0], dy = siy - sj[j4+1][1], dz = siz - sj[j4+1][2];
      o.y = __expf(-100.0f*(dx*dx + dy*dy + dz*dz)) * mk.y; }
    { float dx = six - sj[j4+2][0], dy = siy - sj[j4+2][1], dz = siz - sj[j4+2][2];
      o.z = __expf(-100.0f*(dx*dx + dy*dy + dz*dz)) * mk.z; }
    { float dx = six - sj[j4+3][0], dy = siy - sj[j4+3][1], dz = siz - sj[j4+3][2];
      o.w = __expf(-100.0f*(dx*dx + dy*dy + dz*dz)) * mk.w; }
    *(float4*)&A[base] = o;
  }
}

// ---------------- launcher ----------------

extern "C" void kernel_launch(void* const* d_in, const int* in_sizes, int n_in,
                              void* d_out, int out_size, void* d_ws, size_t ws_size,
                              hipStream_t stream) {
  const float* x      = (const float*)d_in[0];
  const float* mask   = (const float*)d_in[1];
  const float* W_emb  = (const float*)d_in[2];
  const float* b_emb  = (const float*)d_in[3];
  const float* pos    = (const float*)d_in[4];
  const float* Wm     = (const float*)d_in[5];
  const float* bm     = (const float*)d_in[6];
  const float* Wz     = (const float*)d_in[7];
  const float* Uz     = (const float*)d_in[8];
  const float* bz     = (const float*)d_in[9];
  const float* Wr     = (const float*)d_in[10];
  const float* Ur     = (const float*)d_in[11];
  const float* br     = (const float*)d_in[12];
  const float* Wh     = (const float*)d_in[13];
  const float* Uh     = (const float*)d_in[14];
  const float* bh     = (const float*)d_in[15];
  const float* Wpz    = (const float*)d_in[16];
  const float* Upz    = (const float*)d_in[17];
  const float* bpz    = (const float*)d_in[18];
  const float* Wpr    = (const float*)d_in[19];
  const float* Upr    = (const float*)d_in[20];
  const float* bpr    = (const float*)d_in[21];
  const float* Wph    = (const float*)d_in[22];
  const float* Uph    = (const float*)d_in[23];
  const float* bph    = (const float*)d_in[24];

  // d_ws: packed h (16.78MB) + s (0.39MB)  -- same footprint as validated rounds
  u32*   hP = (u32*)d_ws;
  float* s  = (float*)d_ws + (size_t)RTOT * HID;
  // d_out (16.78M floats) as scratch until k_finalA overwrites all of it:
  float* ob   = (float*)d_out;
  u32*   aggP = (u32*)ob;                                   // [0, 4.19M) floats
  short* mtH  = (short*)(ob + (size_t)RTOT * HID);          // 4.19M shorts
  short* mtL  = mtH + (size_t)BSZ * HID * NSEQ;
  short* wpl  = mtL + (size_t)BSZ * HID * NSEQ;             // 21*32768 shorts

  k_prep<<<21, 256, 0, stream>>>(Wm, Wz, Uz, Wr, Ur, Wh, Uh, wpl);
  k_embed<<<RTOT / 32, 256, 0, stream>>>(x, W_emb, b_emb, pos, hP);
  k_sinit<<<RTOT / 256, 256, 0, stream>>>(s);

  for (int i = 0; i < NITER; ++i) {
    const size_t bo = (size_t)i * HID;
    k_msg<<<RTOT / 64, 512, 0, stream>>>(hP, wpl, i, bm + bo, mtH, mtL);
    k_agg<<<dim3(BSZ, NSEQ / 32), 256, 0, stream>>>(s, mask, mtH, mtL, aggP);
    k_zrc<<<RTOT / 64, 512, 0, stream>>>(aggP, hP, wpl, i, bz + bo, br + bo, bh + bo);
    k_posgru<<<RTOT / 4, 256, 0, stream>>>(hP, s, Wpz, Upz, bpz, Wpr, Upr, bpr, Wph, Uph, bph);
  }
  k_finalA<<<dim3(BSZ, NSEQ / 16), 256, 0, stream>>>(s, mask, (float*)d_out);
}

// Round 7
// 489.986 us; speedup vs baseline: 12.7346x; 1.6362x over previous
//
#include <hip/hip_runtime.h>
#include <math.h>

#define BSZ  64
#define NSEQ 512
#define FEAT 64
#define HID  128
#define NITER 3
#define RTOT (BSZ*NSEQ)   // 32768 rows
#define LDAP 136          // padded LDS plane stride (shorts)

typedef __attribute__((ext_vector_type(8))) short bf16x8;
typedef __attribute__((ext_vector_type(4))) float f32x4;
typedef unsigned int u32;

// ---------------- helpers ----------------

__device__ __forceinline__ float sigm(float v) {
  v = fminf(fmaxf(v, -30.f), 30.f);
  return 1.0f / (1.0f + __expf(-v));
}
__device__ __forceinline__ float tanh_fast(float v) {
  v = fminf(fmaxf(v, -15.f), 15.f);
  float e = __expf(2.0f * v);
  return (e - 1.0f) / (e + 1.0f);
}

// split fp32 into (hi,lo) bf16 pair packed in one u32: a ~= f(hi) + f(lo)
__device__ __forceinline__ u32 pack_split(float a) {
  u32 ub = __float_as_uint(a);
  u32 hi = ub >> 16;
  float res = a - __uint_as_float(hi << 16);
  u32 lo = __float_as_uint(res) >> 16;
  return (hi << 16) | lo;
}
__device__ __forceinline__ float bf2f(short v) {
  return __uint_as_float(((u32)(unsigned short)v) << 16);
}

// 3-term split-bf16 product: ah*bh + ah*bl + al*bh
__device__ __forceinline__ f32x4 mfma3(bf16x8 ah, bf16x8 al, bf16x8 bh, bf16x8 bl, f32x4 c) {
  c = __builtin_amdgcn_mfma_f32_16x16x32_bf16(ah, bh, c, 0, 0, 0);
  c = __builtin_amdgcn_mfma_f32_16x16x32_bf16(ah, bl, c, 0, 0, 0);
  c = __builtin_amdgcn_mfma_f32_16x16x32_bf16(al, bh, c, 0, 0, 0);
  return c;
}

// stage packed-u32 [64][128] global tile -> two LDS short planes [64][LDAP]
__device__ __forceinline__ void stage_planes(const u32* __restrict__ g, short* hiP, short* loP, int t) {
  const int row = t >> 3, col = (t & 7) * 16;
  const u32* src = g + (size_t)row * HID + col;
  #pragma unroll
  for (int i = 0; i < 4; ++i) {
    uint4 u = *(const uint4*)(src + i * 4);
    *(short4*)&hiP[row * LDAP + col + i * 4] =
        make_short4((short)(u.x >> 16), (short)(u.y >> 16), (short)(u.z >> 16), (short)(u.w >> 16));
    *(short4*)&loP[row * LDAP + col + i * 4] =
        make_short4((short)(u.x & 0xffff), (short)(u.y & 0xffff), (short)(u.z & 0xffff), (short)(u.w & 0xffff));
  }
}

// one full 128-K gate. A from LDS planes P[AP],P[AP+1]; B from FRAGMENT-BLOCKED
// global weights: per (ks,nh,nt) a contiguous [64][8] hi block then [64][8] lo.
// Wave read = base + l*16B -> fully coalesced 1KB.
// offset(shorts) = ((ks*2 + nh)*4 + nt)*1024 + plane*512 + l*8
#define GATE(ACC, AP, WB) do { \
  _Pragma("unroll") \
  for (int ks_ = 0; ks_ < 4; ++ks_) { \
    bf16x8 ah_ = *(bf16x8*)&P[AP][lrow][ks_*32 + kgrp]; \
    bf16x8 al_ = *(bf16x8*)&P[(AP)+1][lrow][ks_*32 + kgrp]; \
    _Pragma("unroll") \
    for (int nt_ = 0; nt_ < 4; ++nt_) { \
      const short* fb_ = (WB) + (((ks_*2 + nh)*4 + nt_) * 1024) + l * 8; \
      bf16x8 bh_ = *(const bf16x8*)fb_; \
      bf16x8 bl_ = *(const bf16x8*)(fb_ + 512); \
      ACC[nt_] = mfma3(ah_, al_, bh_, bl_, ACC[nt_]); \
    } \
  } \
} while (0)

__device__ __forceinline__ void micro4(const float4 a, const float4 b0, const float4 b1,
                                       const float4 b2, const float4 b3, float acc[4]) {
  acc[0] = fmaf(a.x, b0.x, acc[0]); acc[0] = fmaf(a.y, b1.x, acc[0]);
  acc[0] = fmaf(a.z, b2.x, acc[0]); acc[0] = fmaf(a.w, b3.x, acc[0]);
  acc[1] = fmaf(a.x, b0.y, acc[1]); acc[1] = fmaf(a.y, b1.y, acc[1]);
  acc[1] = fmaf(a.z, b2.y, acc[1]); acc[1] = fmaf(a.w, b3.y, acc[1]);
  acc[2] = fmaf(a.x, b0.z, acc[2]); acc[2] = fmaf(a.y, b1.z, acc[2]);
  acc[2] = fmaf(a.z, b2.z, acc[2]); acc[2] = fmaf(a.w, b3.z, acc[2]);
  acc[3] = fmaf(a.x, b0.w, acc[3]); acc[3] = fmaf(a.y, b1.w, acc[3]);
  acc[3] = fmaf(a.z, b2.w, acc[3]); acc[3] = fmaf(a.w, b3.w, acc[3]);
}

// ---------------- kernels ----------------

// one-time: split the 21 [128][128] weight mats -> fragment-blocked bf16 hi/lo planes.
// mat m = gate*3 + iter, gates: 0=Wm 1=Wz 2=Uz 3=Wr 4=Ur 5=Wh 6=Uh
__global__ __launch_bounds__(256) void k_prep(
    const float* __restrict__ Wm, const float* __restrict__ Wz, const float* __restrict__ Uz,
    const float* __restrict__ Wr, const float* __restrict__ Ur, const float* __restrict__ Wh,
    const float* __restrict__ Uh, short* __restrict__ wpl) {
  __shared__ float Wl[HID * HID];   // 64KB
  const int t = threadIdx.x;
  const int m = blockIdx.x;        // 0..20
  const int g = m / 3, it = m - g * 3;
  const float* src;
  switch (g) { case 0: src = Wm; break; case 1: src = Wz; break; case 2: src = Uz; break;
               case 3: src = Wr; break; case 4: src = Ur; break; case 5: src = Wh; break;
               default: src = Uh; }
  src += (size_t)it * HID * HID;
  for (int i = t; i < HID * HID / 4; i += 256) ((float4*)Wl)[i] = ((const float4*)src)[i];
  __syncthreads();
  short* dst = wpl + (size_t)m * 32768;
  // 2048 lane-slots: s = ((ks*2+nh)*4+nt)*64 + lane
  for (int s = t; s < 2048; s += 256) {
    const int lane = s & 63;
    const int blk = s >> 6;            // (ks*2+nh)*4+nt, 0..31
    const int nt = blk & 3;
    const int nh = (blk >> 2) & 1;
    const int ks = blk >> 3;
    const int n = nh * 64 + nt * 16 + (lane & 15);
    const int k0 = ks * 32 + (lane >> 4) * 8;
    short h8[8], l8[8];
    #pragma unroll
    for (int j = 0; j < 8; ++j) {
      u32 pk = pack_split(Wl[(size_t)(k0 + j) * HID + n]);
      h8[j] = (short)(pk >> 16);
      l8[j] = (short)(pk & 0xffff);
    }
    short* o = dst + blk * 1024 + lane * 8;
    *(bf16x8*)o = *(bf16x8*)h8;
    *(bf16x8*)(o + 512) = *(bf16x8*)l8;
  }
}

// h = relu(x @ W_emb + b_emb) + pos_table[:n] -> packed u32 (fp32 compute, runs once)
__global__ __launch_bounds__(256) void k_embed(const float* __restrict__ x, const float* __restrict__ W,
                                               const float* __restrict__ bias, const float* __restrict__ pos,
                                               u32* __restrict__ hP) {
  __shared__ float xs[32][FEAT];
  const int t = threadIdx.x;
  const int row0 = blockIdx.x * 32;
  {
    const float4* xv = (const float4*)(x + (size_t)row0 * FEAT);
    float4* xd = (float4*)&xs[0][0];
    for (int i = t; i < 32 * FEAT / 4; i += 256) xd[i] = xv[i];
  }
  __syncthreads();
  const int c0 = (t & 31) * 4;
  const int r0 = (t >> 5) * 4;
  float acc[4][4] = {};
  #pragma unroll 2
  for (int k = 0; k < FEAT; k += 4) {
    float4 b0 = *(const float4*)&W[(k + 0) * HID + c0];
    float4 b1 = *(const float4*)&W[(k + 1) * HID + c0];
    float4 b2 = *(const float4*)&W[(k + 2) * HID + c0];
    float4 b3 = *(const float4*)&W[(k + 3) * HID + c0];
    float4 a0 = *(const float4*)&xs[r0 + 0][k];
    float4 a1 = *(const float4*)&xs[r0 + 1][k];
    float4 a2 = *(const float4*)&xs[r0 + 2][k];
    float4 a3 = *(const float4*)&xs[r0 + 3][k];
    micro4(a0, b0, b1, b2, b3, acc[0]);
    micro4(a1, b0, b1, b2, b3, acc[1]);
    micro4(a2, b0, b1, b2, b3, acc[2]);
    micro4(a3, b0, b1, b2, b3, acc[3]);
  }
  const float4 bv = *(const float4*)&bias[c0];
  #pragma unroll
  for (int r = 0; r < 4; ++r) {
    const int row = row0 + r0 + r;
    const int n = row & (NSEQ - 1);
    const float4 pv = *(const float4*)&pos[(size_t)n * HID + c0];
    uint4 pk;
    pk.x = pack_split(fmaxf(acc[r][0] + bv.x, 0.f) + pv.x);
    pk.y = pack_split(fmaxf(acc[r][1] + bv.y, 0.f) + pv.y);
    pk.z = pack_split(fmaxf(acc[r][2] + bv.z, 0.f) + pv.z);
    pk.w = pack_split(fmaxf(acc[r][3] + bv.w, 0.f) + pv.w);
    *(uint4*)&hP[(size_t)row * HID + c0] = pk;
  }
}

__global__ __launch_bounds__(256) void k_sinit(float* __restrict__ s) {
  const int i = blockIdx.x * 256 + threadIdx.x;
  if (i < RTOT) {
    const int n = i & (NSEQ - 1);
    s[(size_t)i * 3 + 0] = ((float)n - (NSEQ - 1) * 0.5f) / (float)NSEQ;
    s[(size_t)i * 3 + 1] = 0.f;
    s[(size_t)i * 3 + 2] = 0.f;
  }
}

// m = relu(h @ Wm + bm) -> FRAGMENT-BLOCKED bf16 planes for k_agg:
// mtB[b][jt(16)][nh(2)][nt(4)][plane(2)][64][8]
__global__ __launch_bounds__(512) void k_msg(const u32* __restrict__ hP, const short* __restrict__ wpl,
                                             int iter, const float* __restrict__ bm,
                                             short* __restrict__ mtB) {
  __shared__ short P[2][64][LDAP];   // h hi/lo planes
  __shared__ short T[2][128][72];    // transpose buffer [n][j-local]
  const int t = threadIdx.x;
  const int row0 = blockIdx.x * 64;
  stage_planes(hP + (size_t)row0 * HID, &P[0][0][0], &P[1][0][0], t);
  __syncthreads();
  const int l = t & 63, w = t >> 6;
  const int mt = w & 3, nh = w >> 2;
  const int lrow = mt * 16 + (l & 15);
  const int kgrp = (l >> 4) * 8;
  const int ncol = l & 15;
  f32x4 z4 = {0.f, 0.f, 0.f, 0.f};
  f32x4 acc[4];
  #pragma unroll
  for (int i = 0; i < 4; ++i) acc[i] = z4;
  GATE(acc, 0, wpl + (size_t)(0 * 3 + iter) * 32768);
  const int rbase = mt * 16 + (l >> 4) * 4;
  #pragma unroll
  for (int nt = 0; nt < 4; ++nt) {
    const int cc = nh * 64 + nt * 16 + ncol;
    const float bmc = bm[cc];
    #pragma unroll
    for (int q = 0; q < 4; ++q) {
      u32 pk = pack_split(fmaxf(acc[nt][q] + bmc, 0.f));
      T[0][cc][rbase + q] = (short)(pk >> 16);
      T[1][cc][rbase + q] = (short)(pk & 0xffff);
    }
  }
  __syncthreads();
  // write out blocked: thread -> n = t>>2, 16 j's at jq=(t&3)*16
  const int b = row0 >> 9, j0 = row0 & (NSEQ - 1);
  const int n = t >> 2, jq = (t & 3) * 16;
  const int nh2 = n >> 6, nt2 = (n >> 4) & 3;
  #pragma unroll
  for (int gch = 0; gch < 2; ++gch) {          // two 8-j groups
    const int jj = jq + gch * 8;               // 0..63 local
    const int jt = (j0 + jj) >> 5;             // global j-tile
    const int jjj = (j0 + jj) & 31;
    const int lane = (jjj >> 3) * 16 + (n & 15);
    #pragma unroll
    for (int pl = 0; pl < 2; ++pl) {
      size_t off = ((((((size_t)b * 16 + jt) * 2 + nh2) * 4 + nt2) * 2 + pl) * 64 + lane) * 8;
      *(bf16x8*)&mtB[off] = *(bf16x8*)&T[pl][n][jj];
    }
  }
}

// agg = (exp(-100 d2)*mask) @ m : exp A-tile in LDS (split bf16, dbuf),
// B from fragment-blocked mtB in global (coalesced 1KB reads).
__global__ __launch_bounds__(256) void k_agg(const float* __restrict__ s, const float* __restrict__ mask,
                                             const short* __restrict__ mtB, u32* __restrict__ aggP) {
  __shared__ float sj[NSEQ][3];
  __shared__ short WH2[2][32][40];
  __shared__ short WL2[2][32][40];
  const int t = threadIdx.x;
  const int b = blockIdx.x;
  const int i0 = blockIdx.y * 32;
  {
    const float* sp = s + (size_t)b * NSEQ * 3;
    for (int i = t; i < NSEQ * 3; i += 256) (&sj[0][0])[i] = sp[i];
  }
  __syncthreads();
  const float* maskb = mask + (size_t)b * NSEQ * NSEQ;
  const int wi = t >> 3, wj4 = (t & 7) * 4;
  const float six = sj[i0 + wi][0], siy = sj[i0 + wi][1], siz = sj[i0 + wi][2];
  {  // slab 0 -> buf 0
    float4 mk = *(const float4*)&maskb[(size_t)(i0 + wi) * NSEQ + wj4];
    float vals[4] = {mk.x, mk.y, mk.z, mk.w};
    short ha[4], la[4];
    #pragma unroll
    for (int c = 0; c < 4; ++c) {
      const int jj = wj4 + c;
      float dx = six - sj[jj][0], dy = siy - sj[jj][1], dz = siz - sj[jj][2];
      u32 pk = pack_split(__expf(-100.0f * (dx * dx + dy * dy + dz * dz)) * vals[c]);
      ha[c] = (short)(pk >> 16); la[c] = (short)(pk & 0xffff);
    }
    *(short4*)&WH2[0][wi][wj4] = make_short4(ha[0], ha[1], ha[2], ha[3]);
    *(short4*)&WL2[0][wi][wj4] = make_short4(la[0], la[1], la[2], la[3]);
  }
  __syncthreads();
  const int l = t & 63, w = t >> 6;
  const int mt = w & 1, nh = w >> 1;
  const int kgrp = (l >> 4) * 8, ncol = l & 15;
  const int arow = mt * 16 + (l & 15);
  f32x4 z4 = {0.f, 0.f, 0.f, 0.f};
  f32x4 acc[4];
  #pragma unroll
  for (int i = 0; i < 4; ++i) acc[i] = z4;
  const short* mtb = mtB + (size_t)b * 131072;
  #pragma unroll 1
  for (int jt = 0; jt < 16; ++jt) {
    const int buf = jt & 1;
    const int jn = (jt + 1) * 32;
    float4 mkn;
    if (jt < 15) mkn = *(const float4*)&maskb[(size_t)(i0 + wi) * NSEQ + jn + wj4];
    bf16x8 ah = *(bf16x8*)&WH2[buf][arow][kgrp];
    bf16x8 al = *(bf16x8*)&WL2[buf][arow][kgrp];
    #pragma unroll
    for (int nt = 0; nt < 4; ++nt) {
      const short* fb = mtb + ((((size_t)jt * 2 + nh) * 4 + nt) * 2) * 512 + l * 8;
      acc[nt] = mfma3(ah, al, *(const bf16x8*)fb, *(const bf16x8*)(fb + 512), acc[nt]);
    }
    if (jt < 15) {
      float vals[4] = {mkn.x, mkn.y, mkn.z, mkn.w};
      short ha[4], la[4];
      #pragma unroll
      for (int c = 0; c < 4; ++c) {
        const int jj = jn + wj4 + c;
        float dx = six - sj[jj][0], dy = siy - sj[jj][1], dz = siz - sj[jj][2];
        u32 pk = pack_split(__expf(-100.0f * (dx * dx + dy * dy + dz * dz)) * vals[c]);
        ha[c] = (short)(pk >> 16); la[c] = (short)(pk & 0xffff);
      }
      *(short4*)&WH2[buf ^ 1][wi][wj4] = make_short4(ha[0], ha[1], ha[2], ha[3]);
      *(short4*)&WL2[buf ^ 1][wi][wj4] = make_short4(la[0], la[1], la[2], la[3]);
    }
    __syncthreads();
  }
  #pragma unroll
  for (int nt = 0; nt < 4; ++nt) {
    const int cc = nh * 64 + nt * 16 + ncol;
    #pragma unroll
    for (int q = 0; q < 4; ++q) {
      const int grow = i0 + mt * 16 + (l >> 4) * 4 + q;
      aggP[((size_t)b * NSEQ + grow) * HID + cc] = pack_split(acc[nt][q]);
    }
  }
}

// fused GRU: 6 gates, rh computed mid-kernel into the h LDS planes. 3 barriers.
__global__ __launch_bounds__(512) void k_zrc(
    const u32* __restrict__ aggP, u32* __restrict__ hP,
    const short* __restrict__ wpl, int iter,
    const float* __restrict__ bz, const float* __restrict__ br, const float* __restrict__ bhh) {
  __shared__ short P[4][64][LDAP];   // 0,1: agg hi/lo; 2,3: h hi/lo (later rh hi/lo)
  const int t = threadIdx.x;
  const int row0 = blockIdx.x * 64;
  stage_planes(aggP + (size_t)row0 * HID, &P[0][0][0], &P[1][0][0], t);
  stage_planes(hP + (size_t)row0 * HID, &P[2][0][0], &P[3][0][0], t);
  __syncthreads();
  const int l = t & 63, w = t >> 6;
  const int mt = w & 3, nh = w >> 2;
  const int lrow = mt * 16 + (l & 15);
  const int kgrp = (l >> 4) * 8;
  const int ncol = l & 15;
  f32x4 z4 = {0.f, 0.f, 0.f, 0.f};
  f32x4 accz[4], accr[4];
  #pragma unroll
  for (int i = 0; i < 4; ++i) { accz[i] = z4; accr[i] = z4; }
  #pragma unroll 1
  for (int g = 0; g < 4; ++g) {   // Wz(agg), Uz(h), Wr(agg), Ur(h)
    const short* WB = wpl + (size_t)((g + 1) * 3 + iter) * 32768;
    const int ap = (g & 1) * 2;
    if (g < 2) { GATE(accz, ap, WB); }
    else       { GATE(accr, ap, WB); }
  }
  const int rbase = mt * 16 + (l >> 4) * 4;
  float hreg[4][4];
  float rhv[4][4];
  #pragma unroll
  for (int nt = 0; nt < 4; ++nt) {
    const int cc = nh * 64 + nt * 16 + ncol;
    const float brc = br[cc];
    #pragma unroll
    for (int q = 0; q < 4; ++q) {
      float hv = bf2f(P[2][rbase + q][cc]) + bf2f(P[3][rbase + q][cc]);
      hreg[nt][q] = hv;
      rhv[nt][q] = sigm(accr[nt][q] + brc) * hv;
    }
  }
  __syncthreads();   // all gates done reading h planes
  #pragma unroll
  for (int nt = 0; nt < 4; ++nt) {
    const int cc = nh * 64 + nt * 16 + ncol;
    #pragma unroll
    for (int q = 0; q < 4; ++q) {
      u32 pk = pack_split(rhv[nt][q]);
      P[2][rbase + q][cc] = (short)(pk >> 16);
      P[3][rbase + q][cc] = (short)(pk & 0xffff);
    }
  }
  __syncthreads();   // rh planes ready
  #pragma unroll
  for (int i = 0; i < 4; ++i) accr[i] = z4;   // reuse as cand accumulator
  GATE(accr, 0, wpl + (size_t)(5 * 3 + iter) * 32768);   // Wh (A=agg)
  GATE(accr, 2, wpl + (size_t)(6 * 3 + iter) * 32768);   // Uh (A=rh)
  #pragma unroll
  for (int nt = 0; nt < 4; ++nt) {
    const int cc = nh * 64 + nt * 16 + ncol;
    const float bzc = bz[cc], bhc = bhh[cc];
    #pragma unroll
    for (int q = 0; q < 4; ++q) {
      float z = sigm(accz[nt][q] + bzc);
      float cand = tanh_fast(accr[nt][q] + bhc);
      float hn = (1.f - z) * hreg[nt][q] + z * cand;
      hP[(size_t)(row0 + rbase + q) * HID + cc] = pack_split(hn);
    }
  }
}

// positional GRU on packed h
__global__ __launch_bounds__(256) void k_posgru(const u32* __restrict__ hP, float* __restrict__ s,
    const float* __restrict__ Wpz, const float* __restrict__ Upz, const float* __restrict__ bpz,
    const float* __restrict__ Wpr, const float* __restrict__ Upr, const float* __restrict__ bpr,
    const float* __restrict__ Wph, const float* __restrict__ Uph, const float* __restrict__ bph) {
  const int lane = threadIdx.x & 63;
  const int w = threadIdx.x >> 6;
  const int row = blockIdx.x * 4 + w;
  const int k0 = lane * 2;
  const uint2 hv2 = *(const uint2*)&hP[(size_t)row * HID + k0];
  const float hx = bf2f((short)(hv2.x >> 16)) + bf2f((short)(hv2.x & 0xffff));
  const float hy = bf2f((short)(hv2.y >> 16)) + bf2f((short)(hv2.y & 0xffff));
  float p[9];
  #pragma unroll
  for (int c = 0; c < 3; ++c) {
    p[c]     = hx * Wpz[k0 * 3 + c] + hy * Wpz[(k0 + 1) * 3 + c];
    p[3 + c] = hx * Wpr[k0 * 3 + c] + hy * Wpr[(k0 + 1) * 3 + c];
    p[6 + c] = hx * Wph[k0 * 3 + c] + hy * Wph[(k0 + 1) * 3 + c];
  }
  #pragma unroll
  for (int off = 32; off > 0; off >>= 1) {
    #pragma unroll
    for (int q = 0; q < 9; ++q) p[q] += __shfl_xor(p[q], off, 64);
  }
  const float s0 = s[(size_t)row * 3 + 0], s1 = s[(size_t)row * 3 + 1], s2 = s[(size_t)row * 3 + 2];
  float zs[3], rs[3], ss[3];
  #pragma unroll
  for (int c = 0; c < 3; ++c) {
    zs[c] = sigm(p[c]     + s0 * Upz[c] + s1 * Upz[3 + c] + s2 * Upz[6 + c] + bpz[c]);
    rs[c] = sigm(p[3 + c] + s0 * Upr[c] + s1 * Upr[3 + c] + s2 * Upr[6 + c] + bpr[c]);
  }
  const float t0 = rs[0] * s0, t1 = rs[1] * s1, t2 = rs[2] * s2;
  #pragma unroll
  for (int c = 0; c < 3; ++c)
    ss[c] = tanh_fast(p[6 + c] + t0 * Uph[c] + t1 * Uph[3 + c] + t2 * Uph[6 + c] + bph[c]);
  if (lane == 0) {
    s[(size_t)row * 3 + 0] = (1.f - zs[0]) * s0 + zs[0] * ss[0];
    s[(size_t)row * 3 + 1] = (1.f - zs[1]) * s1 + zs[1] * ss[1];
    s[(size_t)row * 3 + 2] = (1.f - zs[2]) * s2 + zs[2] * ss[2];
  }
}

// A[b,i,j] = exp(-100*||s_i-s_j||^2)*mask
__global__ __launch_bounds__(256) void k_finalA(const float* __restrict__ s, const float* __restrict__ mask,
                                                float* __restrict__ A) {
  __shared__ float sj[NSEQ][3];
  const int t = threadIdx.x;
  const int b = blockIdx.x;
  const int i0 = blockIdx.y * 16;
  {
    const float* sp = s + (size_t)b * NSEQ * 3;
    for (int i = t; i < NSEQ * 3; i += 256) (&sj[0][0])[i] = sp[i];
  }
  __syncthreads();
  #pragma unroll
  for (int p = 0; p < 8; ++p) {
    const int e = t + p * 256;
    const int ii = e >> 7;
    const int j4 = (e & 127) * 4;
    const float six = sj[i0 + ii][0], siy = sj[i0 + ii][1], siz = sj[i0 + ii][2];
    const size_t base = ((size_t)b * NSEQ + i0 + ii) * NSEQ + j4;
    const float4 mk = *(const float4*)&mask[base];
    float4 o;
    { float dx = six - sj[j4+0][0], dy = siy - sj[j4+0][1], dz = siz - sj[j4+0][2];
      o.x = __expf(-100.0f*(dx*dx + dy*dy + dz*dz)) * mk.x; }
    { float dx = six - sj[j4+1][0], dy = siy - sj[j4+1][1], dz = siz - sj[j4+1][2];
      o.y = __expf(-100.0f*(dx*dx + dy*dy + dz*dz)) * mk.y; }
    { float dx = six - sj[j4+2][0], dy = siy - sj[j4+2][1], dz = siz - sj[j4+2][2];
      o.z = __expf(-100.0f*(dx*dx + dy*dy + dz*dz)) * mk.z; }
    { float dx = six - sj[j4+3][0], dy = siy - sj[j4+3][1], dz = siz - sj[j4+3][2];
      o.w = __expf(-100.0f*(dx*dx + dy*dy + dz*dz)) * mk.w; }
    *(float4*)&A[base] = o;
  }
}

// ---------------- launcher ----------------

extern "C" void kernel_launch(void* const* d_in, const int* in_sizes, int n_in,
                              void* d_out, int out_size, void* d_ws, size_t ws_size,
                              hipStream_t stream) {
  const float* x      = (const float*)d_in[0];
  const float* mask   = (const float*)d_in[1];
  const float* W_emb  = (const float*)d_in[2];
  const float* b_emb  = (const float*)d_in[3];
  const float* pos    = (const float*)d_in[4];
  const float* Wm     = (const float*)d_in[5];
  const float* bm     = (const float*)d_in[6];
  const float* Wz     = (const float*)d_in[7];
  const float* Uz     = (const float*)d_in[8];
  const float* bz     = (const float*)d_in[9];
  const float* Wr     = (const float*)d_in[10];
  const float* Ur     = (const float*)d_in[11];
  const float* br     = (const float*)d_in[12];
  const float* Wh     = (const float*)d_in[13];
  const float* Uh     = (const float*)d_in[14];
  const float* bh     = (const float*)d_in[15];
  const float* Wpz    = (const float*)d_in[16];
  const float* Upz    = (const float*)d_in[17];
  const float* bpz    = (const float*)d_in[18];
  const float* Wpr    = (const float*)d_in[19];
  const float* Upr    = (const float*)d_in[20];
  const float* bpr    = (const float*)d_in[21];
  const float* Wph    = (const float*)d_in[22];
  const float* Uph    = (const float*)d_in[23];
  const float* bph    = (const float*)d_in[24];

  u32*   hP = (u32*)d_ws;
  float* s  = (float*)d_ws + (size_t)RTOT * HID;
  float* ob   = (float*)d_out;
  u32*   aggP = (u32*)ob;                                   // 16.8MB
  short* mtB  = (short*)(ob + (size_t)RTOT * HID);          // 16.8MB (blocked m)
  short* wpl  = mtB + (size_t)BSZ * 131072;                 // 1.4MB (blocked weights)

  k_prep<<<21, 256, 0, stream>>>(Wm, Wz, Uz, Wr, Ur, Wh, Uh, wpl);
  k_embed<<<RTOT / 32, 256, 0, stream>>>(x, W_emb, b_emb, pos, hP);
  k_sinit<<<RTOT / 256, 256, 0, stream>>>(s);

  for (int i = 0; i < NITER; ++i) {
    const size_t bo = (size_t)i * HID;
    k_msg<<<RTOT / 64, 512, 0, stream>>>(hP, wpl, i, bm + bo, mtB);
    k_agg<<<dim3(BSZ, NSEQ / 32), 256, 0, stream>>>(s, mask, mtB, aggP);
    k_zrc<<<RTOT / 64, 512, 0, stream>>>(aggP, hP, wpl, i, bz + bo, br + bo, bh + bo);
    k_posgru<<<RTOT / 4, 256, 0, stream>>>(hP, s, Wpz, Upz, bpz, Wpr, Upr, bpr, Wph, Uph, bph);
  }
  k_finalA<<<dim3(BSZ, NSEQ / 16), 256, 0, stream>>>(s, mask, (float*)d_out);
}